// Round 3
// baseline (362.407 us; speedup 1.0000x reference)
//
#include <hip/hip_runtime.h>
#include <hip/hip_bf16.h>
#include <math.h>

#define NN 1024

typedef __attribute__((ext_vector_type(8))) short bf16x8;
typedef __attribute__((ext_vector_type(4))) float f32x4;

__device__ __forceinline__ float wave_sum(float v) {
#pragma unroll
  for (int off = 32; off > 0; off >>= 1) v += __shfl_down(v, off);
  return v;
}
__device__ __forceinline__ float wave_max(float v) {
#pragma unroll
  for (int off = 32; off > 0; off >>= 1) v = fmaxf(v, __shfl_down(v, off));
  return v;
}
__device__ __forceinline__ short f2bf(float x) {
  __hip_bfloat16 b = __float2bfloat16(x);
  return *(short*)&b;
}

#define SH_C0 0.28209479177387814f
#define SH_C1 0.4886025119029199f
#define SH_S15 1.0925484305920792f
#define SH_S5 0.6307831305050401f

// ---------------------------------------------------------------------------
// K0: transpose the 8 [128x128] weight matrices so GEMV reads are coalesced.
__global__ __launch_bounds__(256) void htr_transpose(
    const float* __restrict__ qw, const float* __restrict__ kw,
    const float* __restrict__ vw, const float* __restrict__ ow,
    float* __restrict__ wT) {
  const int b = blockIdx.x;  // 0..7
  const float* src;
  if (b == 0) src = qw;
  else if (b == 1) src = kw;
  else if (b < 5) src = vw + (b - 2) * 16384;
  else src = ow + (b - 5) * 16384;
  float* dst = wT + b * 16384;
  for (int idx = threadIdx.x; idx < 16384; idx += 256) {
    int r = idx >> 7, cc = idx & 127;
    dst[cc * 128 + r] = src[idx];
  }
}

// ---------------------------------------------------------------------------
// K1: S_row[i][m] = (1/N) sum_j valid(i,j) * sh_m(r_hat(i,j))
__global__ __launch_bounds__(256) void htr_row_stats(
    const float* __restrict__ pos, const int* __restrict__ batch,
    float* __restrict__ S_row) {
  const int i = blockIdx.x;
  const int tid = threadIdx.x;
  const float px = pos[i * 3 + 0], py = pos[i * 3 + 1], pz = pos[i * 3 + 2];
  const int bi = batch[i];
  float s[9];
#pragma unroll
  for (int m = 0; m < 9; ++m) s[m] = 0.f;
  for (int j = tid; j < NN; j += 256) {
    if (j == i) continue;
    if (batch[j] != bi) continue;
    float dx = px - pos[j * 3 + 0];
    float dy = py - pos[j * 3 + 1];
    float dz = pz - pos[j * 3 + 2];
    float d2 = dx * dx + dy * dy + dz * dz;
    float dist = fmaxf(sqrtf(d2), 1e-8f);
    float inv = 1.0f / dist;
    float x = dx * inv, y = dy * inv, z = dz * inv;
    s[0] += 1.0f;
    s[1] += x; s[2] += y; s[3] += z;
    s[4] += x * z; s[5] += x * y;
    s[6] += y * y - 0.5f * (x * x + z * z);
    s[7] += y * z;
    s[8] += z * z - x * x;
  }
  __shared__ float red[4][9];
  const int wave = tid >> 6, lane = tid & 63;
#pragma unroll
  for (int m = 0; m < 9; ++m) {
    float v = wave_sum(s[m]);
    if (lane == 0) red[wave][m] = v;
  }
  __syncthreads();
  if (tid < 9) {
    float v = red[0][tid] + red[1][tid] + red[2][tid] + red[3][tid];
    float scl = SH_S15;
    if (tid == 0) scl = SH_C0;
    else if (tid < 4) scl = SH_C1;
    else if (tid == 6) scl = SH_S5;
    else if (tid == 8) scl = 0.5f * SH_S15;
    S_row[i * 9 + tid] = v * scl * (1.0f / 1024.0f);
  }
}

// ---------------------------------------------------------------------------
// K2: rowmean[i,c] = sum_m S_row[i,m] * invdeg(m) * x_emb[i,m,c]
__global__ __launch_bounds__(128) void htr_rowmean(
    const float* __restrict__ x_emb, const float* __restrict__ S_row,
    float* __restrict__ rowm) {
  const int i = blockIdx.x;
  const int c = threadIdx.x;
  float acc = 0.f;
#pragma unroll
  for (int m = 0; m < 9; ++m) {
    float idg = (m == 0) ? 1.f : ((m < 4) ? (1.f / 3.f) : 0.2f);
    acc = fmaf(S_row[i * 9 + m] * idg, x_emb[(i * 9 + m) * 128 + c], acc);
  }
  rowm[i * 128 + c] = acc;
}

// ---------------------------------------------------------------------------
// K3: colmean partials. 8 j per block, i split 8 ways, 4-i LDS tiles.
#define CM_J 8
#define CM_TI 4
#define CM_ISPLIT 8
__global__ __launch_bounds__(256) void htr_colmean(
    const float* __restrict__ x_emb, const float* __restrict__ pos,
    const int* __restrict__ batch, float* __restrict__ part) {
  const int jbase = blockIdx.x * CM_J;
  const int tid = threadIdx.x;
  const int jp = tid >> 7;
  const int c = tid & 127;
  __shared__ __align__(16) float fs[CM_TI][9][128];
  __shared__ __align__(16) float wsm[CM_TI][9][CM_J];
  __shared__ float pj[CM_J][3];
  __shared__ int bj[CM_J];
  if (tid < CM_J) {
    int j = jbase + tid;
    pj[tid][0] = pos[j * 3 + 0];
    pj[tid][1] = pos[j * 3 + 1];
    pj[tid][2] = pos[j * 3 + 2];
    bj[tid] = batch[j];
  }
  __syncthreads();
  float acc[4] = {0.f, 0.f, 0.f, 0.f};
  const int i_begin = blockIdx.y * (1024 / CM_ISPLIT);
  for (int i0 = i_begin; i0 < i_begin + (1024 / CM_ISPLIT); i0 += CM_TI) {
    const float2* src = (const float2*)(x_emb + i0 * 1152);
    float2* dst = (float2*)(&fs[0][0][0]);
#pragma unroll
    for (int it = 0; it < 9; ++it) dst[tid + it * 256] = src[tid + it * 256];
    if (tid < CM_TI * CM_J) {
      int ii = tid >> 3, tj = tid & 7;
      int i = i0 + ii;
      int j = jbase + tj;
      float dx = pos[i * 3 + 0] - pj[tj][0];
      float dy = pos[i * 3 + 1] - pj[tj][1];
      float dz = pos[i * 3 + 2] - pj[tj][2];
      bool ok = (i != j) && (batch[i] == bj[tj]);
      float okf = ok ? 1.f : 0.f;
      float d2 = dx * dx + dy * dy + dz * dz;
      float inv = okf / fmaxf(sqrtf(d2), 1e-8f);
      float x = dx * inv, y = dy * inv, z = dz * inv;
      wsm[ii][0][tj] = SH_C0 * okf;
      wsm[ii][1][tj] = (SH_C1 * (1.f / 3.f)) * x;
      wsm[ii][2][tj] = (SH_C1 * (1.f / 3.f)) * y;
      wsm[ii][3][tj] = (SH_C1 * (1.f / 3.f)) * z;
      wsm[ii][4][tj] = (SH_S15 * 0.2f) * x * z;
      wsm[ii][5][tj] = (SH_S15 * 0.2f) * x * y;
      wsm[ii][6][tj] = (SH_S5 * 0.2f) * (y * y - 0.5f * (x * x + z * z));
      wsm[ii][7][tj] = (SH_S15 * 0.2f) * y * z;
      wsm[ii][8][tj] = (0.5f * SH_S15 * 0.2f) * (z * z - x * x);
    }
    __syncthreads();
#pragma unroll
    for (int ii = 0; ii < CM_TI; ++ii) {
#pragma unroll
      for (int m = 0; m < 9; ++m) {
        float4 w4 = *(const float4*)(&wsm[ii][m][jp * 4]);
        float f = fs[ii][m][c];
        acc[0] = fmaf(w4.x, f, acc[0]);
        acc[1] = fmaf(w4.y, f, acc[1]);
        acc[2] = fmaf(w4.z, f, acc[2]);
        acc[3] = fmaf(w4.w, f, acc[3]);
      }
    }
    __syncthreads();
  }
#pragma unroll
  for (int r = 0; r < 4; ++r)
    part[(blockIdx.y * 1024 + jbase + jp * 4 + r) * 128 + c] = acc[r];
}

// ---------------------------------------------------------------------------
// K3b: dst[t] = scale * sum_s src[s*n + t]
__global__ __launch_bounds__(256) void htr_reduce(
    const float* __restrict__ src, float* __restrict__ dst, int n, int nsl,
    float scale) {
  int t = blockIdx.x * 256 + threadIdx.x;
  if (t >= n) return;
  float a = 0.f;
  for (int s = 0; s < nsl; ++s) a += src[s * n + t];
  dst[t] = a * scale;
}

// ---------------------------------------------------------------------------
// K4: q = rowmean @ q_w^T + q_b   (layout [i][c])
//     k = colmean @ k_w^T + k_b   (layout [h][j][d])
__global__ __launch_bounds__(128) void htr_qk(
    const float* __restrict__ rowm, const float* __restrict__ colm,
    const float* __restrict__ wT, const float* __restrict__ q_b,
    const float* __restrict__ k_b, float* __restrict__ qbuf,
    float* __restrict__ khbuf) {
  const int b = blockIdx.x;
  const bool isq = b < 1024;
  const int i = isq ? b : (b - 1024);
  const float* src = isq ? (rowm + i * 128) : (colm + i * 128);
  const float* w = wT + (isq ? 0 : 16384);
  const int co = threadIdx.x;
  __shared__ float s[128];
  s[co] = src[co];
  __syncthreads();
  float acc = isq ? q_b[co] : k_b[co];
#pragma unroll 8
  for (int ci = 0; ci < 128; ++ci) acc = fmaf(s[ci], w[ci * 128 + co], acc);
  if (isq) qbuf[i * 128 + co] = acc;
  else khbuf[((co >> 4) * 1024 + i) * 16 + (co & 15)] = acc;
}

// ---------------------------------------------------------------------------
// K5: attn[h,i,:] = softmax_j (q_ih . k_jh)/4, masked to same batch. BF16 out.
__global__ __launch_bounds__(256) void htr_attn(
    const float* __restrict__ qbuf, const float* __restrict__ khbuf,
    const int* __restrict__ batch, short* __restrict__ attn) {
  const int i = blockIdx.x;
  const int h = blockIdx.y;
  const int tid = threadIdx.x;
  __shared__ float qv[16];
  __shared__ float redm[4], reds[4];
  if (tid < 16) qv[tid] = qbuf[i * 128 + h * 16 + tid] * 0.25f;
  __syncthreads();
  const int bi = batch[i];
  float l[4];
#pragma unroll
  for (int p = 0; p < 4; ++p) {
    int j = tid + (p << 8);
    float acc = -INFINITY;
    if (batch[j] == bi) {
      const float4* kp = (const float4*)(khbuf + (h * 1024 + j) * 16);
      float4 k0 = kp[0], k1 = kp[1], k2 = kp[2], k3 = kp[3];
      float d = 0.f;
      d = fmaf(qv[0], k0.x, d);  d = fmaf(qv[1], k0.y, d);
      d = fmaf(qv[2], k0.z, d);  d = fmaf(qv[3], k0.w, d);
      d = fmaf(qv[4], k1.x, d);  d = fmaf(qv[5], k1.y, d);
      d = fmaf(qv[6], k1.z, d);  d = fmaf(qv[7], k1.w, d);
      d = fmaf(qv[8], k2.x, d);  d = fmaf(qv[9], k2.y, d);
      d = fmaf(qv[10], k2.z, d); d = fmaf(qv[11], k2.w, d);
      d = fmaf(qv[12], k3.x, d); d = fmaf(qv[13], k3.y, d);
      d = fmaf(qv[14], k3.z, d); d = fmaf(qv[15], k3.w, d);
      acc = d;
    }
    l[p] = acc;
  }
  const int wave = tid >> 6, lane = tid & 63;
  float mx = fmaxf(fmaxf(l[0], l[1]), fmaxf(l[2], l[3]));
  mx = wave_max(mx);
  if (lane == 0) redm[wave] = mx;
  __syncthreads();
  const float M = fmaxf(fmaxf(redm[0], redm[1]), fmaxf(redm[2], redm[3]));
  float e[4];
  float ssum = 0.f;
#pragma unroll
  for (int p = 0; p < 4; ++p) { e[p] = expf(l[p] - M); ssum += e[p]; }
  ssum = wave_sum(ssum);
  if (lane == 0) reds[wave] = ssum;
  __syncthreads();
  const float inv = 1.0f / (reds[0] + reds[1] + reds[2] + reds[3]);
  short* dstp = attn + (h * 1024 + i) * 1024;
#pragma unroll
  for (int p = 0; p < 4; ++p) dstp[tid + (p << 8)] = f2bf(e[p] * inv);
}

// ---------------------------------------------------------------------------
// K6: vbuf[j,m,:] = x_emb[j,m,:] @ v_w[l(m)]^T (+ v_b0 when m==0)
__global__ __launch_bounds__(128) void htr_vproj(
    const float* __restrict__ x_emb, const float* __restrict__ wT,
    const float* __restrict__ v_b0, float* __restrict__ vbuf) {
  const int bm = blockIdx.x;  // i*9+m
  const int m = bm % 9;
  const int l = (m == 0) ? 0 : ((m < 4) ? 1 : 2);
  const float* w = wT + (2 + l) * 16384;
  const int co = threadIdx.x;
  __shared__ float s[128];
  s[co] = x_emb[bm * 128 + co];
  __syncthreads();
  float acc = (m == 0) ? v_b0[co] : 0.f;
#pragma unroll 8
  for (int ci = 0; ci < 128; ++ci) acc = fmaf(s[ci], w[ci * 128 + co], acc);
  vbuf[bm * 128 + co] = acc;
}

// ---------------------------------------------------------------------------
// K7: o[i,m,c] = sum_j attn[h(c),i,j] * v[j,m,c]  as per-head MFMA GEMM:
// per head h: O[1024 x 144] = A[1024 x 1024] * V[1024 x 144]  (n=(m,d))
// grid (itile 32, ntile 3, head 8), 128 thr = 2 waves; each wave 16 i x 48 n.
// LDS: A tile [32 i][32 k] bf16, V tile [48 n][32 k] bf16 (both +8 pad for
// conflict-free ds_read_b128). Fragment maps (m89-verified):
//   A: lane holds A[m=lane&15][k=quad*8+r]; B: B[k=quad*8+r][n=lane&15];
//   C/D: col=lane&15, row=quad*4+reg.
__global__ __launch_bounds__(128) void htr_apply_mfma(
    const short* __restrict__ attn,   // [h][i][j] bf16
    const float* __restrict__ vbuf,   // [j][m][c] fp32
    float* __restrict__ obuf) {       // [i][m][c] fp32
  const int itile = blockIdx.x;
  const int ntile = blockIdx.y;
  const int h = blockIdx.z;
  const int tid = threadIdx.x;
  const int wv = tid >> 6;
  const int lane = tid & 63;
  const int q = lane >> 4;
  const int l15 = lane & 15;
  const int ibase = itile * 32;
  const int nbase = ntile * 48;
  __shared__ __align__(16) short as_[32][40];
  __shared__ __align__(16) short vs_[48][40];
  f32x4 acc[3];
#pragma unroll
  for (int t = 0; t < 3; ++t) acc[t] = (f32x4){0.f, 0.f, 0.f, 0.f};
  const short* abase = attn + (h * 1024 + ibase) * 1024;
  const int arow = tid >> 2, ach = tid & 3;
  for (int k0 = 0; k0 < 1024; k0 += 32) {
    // stage A: 32x32 bf16; thread -> row tid>>2, 8-elem chunk tid&3
    *(int4*)(&as_[arow][ach * 8]) =
        *(const int4*)(abase + arow * 1024 + k0 + ach * 8);
    // stage V: 48n x 32k fp32 -> bf16 transposed; 1536 elems, 12/thread
#pragma unroll
    for (int p = 0; p < 12; ++p) {
      int e = tid + p * 128;
      int n = e % 48, k = e / 48;
      int ng = nbase + n;
      float v = vbuf[(k0 + k) * 1152 + (ng >> 4) * 128 + h * 16 + (ng & 15)];
      vs_[n][k] = f2bf(v);
    }
    __syncthreads();
    bf16x8 a = *(const bf16x8*)(&as_[wv * 16 + l15][q * 8]);
#pragma unroll
    for (int t = 0; t < 3; ++t) {
      bf16x8 b = *(const bf16x8*)(&vs_[t * 16 + l15][q * 8]);
      acc[t] = __builtin_amdgcn_mfma_f32_16x16x32_bf16(a, b, acc[t], 0, 0, 0);
    }
    __syncthreads();
  }
#pragma unroll
  for (int t = 0; t < 3; ++t) {
    int ng = nbase + t * 16 + l15;
    int m = ng >> 4, d = ng & 15;
#pragma unroll
    for (int r = 0; r < 4; ++r) {
      int i = ibase + wv * 16 + q * 4 + r;
      obuf[(i * 9 + m) * 128 + h * 16 + d] = acc[t][r];
    }
  }
}

// ---------------------------------------------------------------------------
// K8: out[i,m,:] = LayerNorm(x_emb[i,m,:] + obuf[i,m,:] @ out_w[l]^T)
__global__ __launch_bounds__(128) void htr_outln(
    const float* __restrict__ x_emb, const float* __restrict__ obuf,
    const float* __restrict__ wT, const float* __restrict__ ln_g,
    const float* __restrict__ ln_b, float* __restrict__ out) {
  const int bm = blockIdx.x;  // i*9+m
  const int m = bm % 9;
  const int l = (m == 0) ? 0 : ((m < 4) ? 1 : 2);
  const float* w = wT + (5 + l) * 16384;
  const int co = threadIdx.x;
  __shared__ float s[128];
  __shared__ float r1[2], r2[2];
  s[co] = obuf[bm * 128 + co];
  __syncthreads();
  float acc = 0.f;
#pragma unroll 8
  for (int ci = 0; ci < 128; ++ci) acc = fmaf(s[ci], w[ci * 128 + co], acc);
  float t = x_emb[bm * 128 + co] + acc;
  const int wave = co >> 6, lane = co & 63;
  float sv = wave_sum(t);
  float sq = wave_sum(t * t);
  if (lane == 0) { r1[wave] = sv; r2[wave] = sq; }
  __syncthreads();
  const float mu = (r1[0] + r1[1]) * (1.0f / 128.0f);
  const float ms = (r2[0] + r2[1]) * (1.0f / 128.0f);
  const float var = ms - mu * mu;
  out[bm * 128 + co] =
      (t - mu) * rsqrtf(var + 1e-5f) * ln_g[l * 128 + co] + ln_b[l * 128 + co];
}

// ---------------------------------------------------------------------------
extern "C" void kernel_launch(void* const* d_in, const int* in_sizes, int n_in,
                              void* d_out, int out_size, void* d_ws, size_t ws_size,
                              hipStream_t stream) {
  (void)in_sizes; (void)n_in; (void)out_size; (void)ws_size;
  const float* x_emb = (const float*)d_in[0];
  const float* pos   = (const float*)d_in[1];
  const float* q_w   = (const float*)d_in[2];
  const float* q_b   = (const float*)d_in[3];
  const float* k_w   = (const float*)d_in[4];
  const float* k_b   = (const float*)d_in[5];
  const float* v_w   = (const float*)d_in[6];
  const float* v_b0  = (const float*)d_in[7];
  const float* out_w = (const float*)d_in[8];
  const float* ln_g  = (const float*)d_in[9];
  const float* ln_b  = (const float*)d_in[10];
  const int*   batch = (const int*)d_in[11];
  float* out = (float*)d_out;

  // workspace layout (float offsets)
  float* ws    = (float*)d_ws;
  float* S_row = ws;              //   9,216
  float* rowm  = ws + 16384;      // 131,072
  float* colm  = ws + 147456;     // 131,072
  float* qbuf  = ws + 278528;     // 131,072
  float* khbuf = ws + 409600;     // 131,072  [h][j][d]
  float* wT    = ws + 540672;     // 131,072
  float* vbuf  = ws + 671744;     // 1,179,648
  float* obuf  = ws + 1851392;    // 1,179,648
  short* attn  = (short*)(ws + 3031040);  // 8,388,608 bf16 [h][i][j]
  float* part  = ws + 3031040;    // colmean partials alias attn region
                                  // (attn written only after reduce)

  htr_transpose<<<8, 256, 0, stream>>>(q_w, k_w, v_w, out_w, wT);
  htr_row_stats<<<1024, 256, 0, stream>>>(pos, batch, S_row);
  htr_rowmean<<<1024, 128, 0, stream>>>(x_emb, S_row, rowm);
  htr_colmean<<<dim3(1024 / CM_J, CM_ISPLIT), 256, 0, stream>>>(x_emb, pos,
                                                                batch, part);
  htr_reduce<<<512, 256, 0, stream>>>(part, colm, 131072, CM_ISPLIT,
                                      1.0f / 1024.0f);
  htr_qk<<<2048, 128, 0, stream>>>(rowm, colm, wT, q_b, k_b, qbuf, khbuf);
  htr_attn<<<dim3(1024, 8), 256, 0, stream>>>(qbuf, khbuf, batch, attn);
  htr_vproj<<<9216, 128, 0, stream>>>(x_emb, wT, v_b0, vbuf);
  htr_apply_mfma<<<dim3(32, 3, 8), 128, 0, stream>>>(attn, vbuf, obuf);
  htr_outln<<<9216, 128, 0, stream>>>(x_emb, obuf, wT, ln_g, ln_b, out);
}

// Round 4
// 274.057 us; speedup vs baseline: 1.3224x; 1.3224x over previous
//
#include <hip/hip_runtime.h>
#include <hip/hip_bf16.h>
#include <math.h>

#define NN 1024

typedef __attribute__((ext_vector_type(8))) short bf16x8;
typedef __attribute__((ext_vector_type(4))) float f32x4;

__device__ __forceinline__ float wave_sum(float v) {
#pragma unroll
  for (int off = 32; off > 0; off >>= 1) v += __shfl_down(v, off);
  return v;
}
__device__ __forceinline__ float wave_max(float v) {
#pragma unroll
  for (int off = 32; off > 0; off >>= 1) v = fmaxf(v, __shfl_down(v, off));
  return v;
}
__device__ __forceinline__ short f2bf(float x) {
  __hip_bfloat16 b = __float2bfloat16(x);
  return *(short*)&b;
}

#define SH_C0 0.28209479177387814f
#define SH_C1 0.4886025119029199f
#define SH_S15 1.0925484305920792f
#define SH_S5 0.6307831305050401f

// ---------------------------------------------------------------------------
// K0: transpose the 8 [128x128] weight matrices so GEMV reads are coalesced.
__global__ __launch_bounds__(256) void htr_transpose(
    const float* __restrict__ qw, const float* __restrict__ kw,
    const float* __restrict__ vw, const float* __restrict__ ow,
    float* __restrict__ wT) {
  const int b = blockIdx.x;  // 0..7
  const float* src;
  if (b == 0) src = qw;
  else if (b == 1) src = kw;
  else if (b < 5) src = vw + (b - 2) * 16384;
  else src = ow + (b - 5) * 16384;
  float* dst = wT + b * 16384;
  for (int idx = threadIdx.x; idx < 16384; idx += 256) {
    int r = idx >> 7, cc = idx & 127;
    dst[cc * 128 + r] = src[idx];
  }
}

// ---------------------------------------------------------------------------
// K1: S_row[i][m] = (1/N) sum_j valid(i,j) * sh_m(r_hat(i,j))
__global__ __launch_bounds__(256) void htr_row_stats(
    const float* __restrict__ pos, const int* __restrict__ batch,
    float* __restrict__ S_row) {
  const int i = blockIdx.x;
  const int tid = threadIdx.x;
  const float px = pos[i * 3 + 0], py = pos[i * 3 + 1], pz = pos[i * 3 + 2];
  const int bi = batch[i];
  float s[9];
#pragma unroll
  for (int m = 0; m < 9; ++m) s[m] = 0.f;
  for (int j = tid; j < NN; j += 256) {
    if (j == i) continue;
    if (batch[j] != bi) continue;
    float dx = px - pos[j * 3 + 0];
    float dy = py - pos[j * 3 + 1];
    float dz = pz - pos[j * 3 + 2];
    float d2 = dx * dx + dy * dy + dz * dz;
    float dist = fmaxf(sqrtf(d2), 1e-8f);
    float inv = 1.0f / dist;
    float x = dx * inv, y = dy * inv, z = dz * inv;
    s[0] += 1.0f;
    s[1] += x; s[2] += y; s[3] += z;
    s[4] += x * z; s[5] += x * y;
    s[6] += y * y - 0.5f * (x * x + z * z);
    s[7] += y * z;
    s[8] += z * z - x * x;
  }
  __shared__ float red[4][9];
  const int wave = tid >> 6, lane = tid & 63;
#pragma unroll
  for (int m = 0; m < 9; ++m) {
    float v = wave_sum(s[m]);
    if (lane == 0) red[wave][m] = v;
  }
  __syncthreads();
  if (tid < 9) {
    float v = red[0][tid] + red[1][tid] + red[2][tid] + red[3][tid];
    float scl = SH_S15;
    if (tid == 0) scl = SH_C0;
    else if (tid < 4) scl = SH_C1;
    else if (tid == 6) scl = SH_S5;
    else if (tid == 8) scl = 0.5f * SH_S15;
    S_row[i * 9 + tid] = v * scl * (1.0f / 1024.0f);
  }
}

// ---------------------------------------------------------------------------
// K2: rowmean[i,c] = sum_m S_row[i,m] * invdeg(m) * x_emb[i,m,c]
__global__ __launch_bounds__(128) void htr_rowmean(
    const float* __restrict__ x_emb, const float* __restrict__ S_row,
    float* __restrict__ rowm) {
  const int i = blockIdx.x;
  const int c = threadIdx.x;
  float acc = 0.f;
#pragma unroll
  for (int m = 0; m < 9; ++m) {
    float idg = (m == 0) ? 1.f : ((m < 4) ? (1.f / 3.f) : 0.2f);
    acc = fmaf(S_row[i * 9 + m] * idg, x_emb[(i * 9 + m) * 128 + c], acc);
  }
  rowm[i * 128 + c] = acc;
}

// ---------------------------------------------------------------------------
// K3: colmean partials. 8 j per block, i split 8 ways, 4-i LDS tiles.
#define CM_J 8
#define CM_TI 4
#define CM_ISPLIT 8
__global__ __launch_bounds__(256) void htr_colmean(
    const float* __restrict__ x_emb, const float* __restrict__ pos,
    const int* __restrict__ batch, float* __restrict__ part) {
  const int jbase = blockIdx.x * CM_J;
  const int tid = threadIdx.x;
  const int jp = tid >> 7;
  const int c = tid & 127;
  __shared__ __align__(16) float fs[CM_TI][9][128];
  __shared__ __align__(16) float wsm[CM_TI][9][CM_J];
  __shared__ float pj[CM_J][3];
  __shared__ int bj[CM_J];
  if (tid < CM_J) {
    int j = jbase + tid;
    pj[tid][0] = pos[j * 3 + 0];
    pj[tid][1] = pos[j * 3 + 1];
    pj[tid][2] = pos[j * 3 + 2];
    bj[tid] = batch[j];
  }
  __syncthreads();
  float acc[4] = {0.f, 0.f, 0.f, 0.f};
  const int i_begin = blockIdx.y * (1024 / CM_ISPLIT);
  for (int i0 = i_begin; i0 < i_begin + (1024 / CM_ISPLIT); i0 += CM_TI) {
    const float2* src = (const float2*)(x_emb + i0 * 1152);
    float2* dst = (float2*)(&fs[0][0][0]);
#pragma unroll
    for (int it = 0; it < 9; ++it) dst[tid + it * 256] = src[tid + it * 256];
    if (tid < CM_TI * CM_J) {
      int ii = tid >> 3, tj = tid & 7;
      int i = i0 + ii;
      int j = jbase + tj;
      float dx = pos[i * 3 + 0] - pj[tj][0];
      float dy = pos[i * 3 + 1] - pj[tj][1];
      float dz = pos[i * 3 + 2] - pj[tj][2];
      bool ok = (i != j) && (batch[i] == bj[tj]);
      float okf = ok ? 1.f : 0.f;
      float d2 = dx * dx + dy * dy + dz * dz;
      float inv = okf / fmaxf(sqrtf(d2), 1e-8f);
      float x = dx * inv, y = dy * inv, z = dz * inv;
      wsm[ii][0][tj] = SH_C0 * okf;
      wsm[ii][1][tj] = (SH_C1 * (1.f / 3.f)) * x;
      wsm[ii][2][tj] = (SH_C1 * (1.f / 3.f)) * y;
      wsm[ii][3][tj] = (SH_C1 * (1.f / 3.f)) * z;
      wsm[ii][4][tj] = (SH_S15 * 0.2f) * x * z;
      wsm[ii][5][tj] = (SH_S15 * 0.2f) * x * y;
      wsm[ii][6][tj] = (SH_S5 * 0.2f) * (y * y - 0.5f * (x * x + z * z));
      wsm[ii][7][tj] = (SH_S15 * 0.2f) * y * z;
      wsm[ii][8][tj] = (0.5f * SH_S15 * 0.2f) * (z * z - x * x);
    }
    __syncthreads();
#pragma unroll
    for (int ii = 0; ii < CM_TI; ++ii) {
#pragma unroll
      for (int m = 0; m < 9; ++m) {
        float4 w4 = *(const float4*)(&wsm[ii][m][jp * 4]);
        float f = fs[ii][m][c];
        acc[0] = fmaf(w4.x, f, acc[0]);
        acc[1] = fmaf(w4.y, f, acc[1]);
        acc[2] = fmaf(w4.z, f, acc[2]);
        acc[3] = fmaf(w4.w, f, acc[3]);
      }
    }
    __syncthreads();
  }
#pragma unroll
  for (int r = 0; r < 4; ++r)
    part[(blockIdx.y * 1024 + jbase + jp * 4 + r) * 128 + c] = acc[r];
}

// ---------------------------------------------------------------------------
// K3b: dst[t] = scale * sum_s src[s*n + t]
__global__ __launch_bounds__(256) void htr_reduce(
    const float* __restrict__ src, float* __restrict__ dst, int n, int nsl,
    float scale) {
  int t = blockIdx.x * 256 + threadIdx.x;
  if (t >= n) return;
  float a = 0.f;
  for (int s = 0; s < nsl; ++s) a += src[s * n + t];
  dst[t] = a * scale;
}

// ---------------------------------------------------------------------------
// K4: q = rowmean @ q_w^T + q_b   (layout [i][c])
//     k = colmean @ k_w^T + k_b   (layout [h][j][d])
__global__ __launch_bounds__(128) void htr_qk(
    const float* __restrict__ rowm, const float* __restrict__ colm,
    const float* __restrict__ wT, const float* __restrict__ q_b,
    const float* __restrict__ k_b, float* __restrict__ qbuf,
    float* __restrict__ khbuf) {
  const int b = blockIdx.x;
  const bool isq = b < 1024;
  const int i = isq ? b : (b - 1024);
  const float* src = isq ? (rowm + i * 128) : (colm + i * 128);
  const float* w = wT + (isq ? 0 : 16384);
  const int co = threadIdx.x;
  __shared__ float s[128];
  s[co] = src[co];
  __syncthreads();
  float acc = isq ? q_b[co] : k_b[co];
#pragma unroll 8
  for (int ci = 0; ci < 128; ++ci) acc = fmaf(s[ci], w[ci * 128 + co], acc);
  if (isq) qbuf[i * 128 + co] = acc;
  else khbuf[((co >> 4) * 1024 + i) * 16 + (co & 15)] = acc;
}

// ---------------------------------------------------------------------------
// K5: attn[h,i,:] = softmax_j (q_ih . k_jh)/4, masked to same batch. BF16 out.
__global__ __launch_bounds__(256) void htr_attn(
    const float* __restrict__ qbuf, const float* __restrict__ khbuf,
    const int* __restrict__ batch, short* __restrict__ attn) {
  const int i = blockIdx.x;
  const int h = blockIdx.y;
  const int tid = threadIdx.x;
  __shared__ float qv[16];
  __shared__ float redm[4], reds[4];
  if (tid < 16) qv[tid] = qbuf[i * 128 + h * 16 + tid] * 0.25f;
  __syncthreads();
  const int bi = batch[i];
  float l[4];
#pragma unroll
  for (int p = 0; p < 4; ++p) {
    int j = tid + (p << 8);
    float acc = -INFINITY;
    if (batch[j] == bi) {
      const float4* kp = (const float4*)(khbuf + (h * 1024 + j) * 16);
      float4 k0 = kp[0], k1 = kp[1], k2 = kp[2], k3 = kp[3];
      float d = 0.f;
      d = fmaf(qv[0], k0.x, d);  d = fmaf(qv[1], k0.y, d);
      d = fmaf(qv[2], k0.z, d);  d = fmaf(qv[3], k0.w, d);
      d = fmaf(qv[4], k1.x, d);  d = fmaf(qv[5], k1.y, d);
      d = fmaf(qv[6], k1.z, d);  d = fmaf(qv[7], k1.w, d);
      d = fmaf(qv[8], k2.x, d);  d = fmaf(qv[9], k2.y, d);
      d = fmaf(qv[10], k2.z, d); d = fmaf(qv[11], k2.w, d);
      d = fmaf(qv[12], k3.x, d); d = fmaf(qv[13], k3.y, d);
      d = fmaf(qv[14], k3.z, d); d = fmaf(qv[15], k3.w, d);
      acc = d;
    }
    l[p] = acc;
  }
  const int wave = tid >> 6, lane = tid & 63;
  float mx = fmaxf(fmaxf(l[0], l[1]), fmaxf(l[2], l[3]));
  mx = wave_max(mx);
  if (lane == 0) redm[wave] = mx;
  __syncthreads();
  const float M = fmaxf(fmaxf(redm[0], redm[1]), fmaxf(redm[2], redm[3]));
  float e[4];
  float ssum = 0.f;
#pragma unroll
  for (int p = 0; p < 4; ++p) { e[p] = expf(l[p] - M); ssum += e[p]; }
  ssum = wave_sum(ssum);
  if (lane == 0) reds[wave] = ssum;
  __syncthreads();
  const float inv = 1.0f / (reds[0] + reds[1] + reds[2] + reds[3]);
  short* dstp = attn + (h * 1024 + i) * 1024;
#pragma unroll
  for (int p = 0; p < 4; ++p) dstp[tid + (p << 8)] = f2bf(e[p] * inv);
}

// ---------------------------------------------------------------------------
// K6: v = x_emb[j,m,:] @ v_w[l(m)]^T (+ v_b0 when m==0), written DIRECTLY as
// bf16 in MFMA-B layout: vbT[h][n][k] with n = m*16+d, k = j.
__global__ __launch_bounds__(128) void htr_vproj(
    const float* __restrict__ x_emb, const float* __restrict__ wT,
    const float* __restrict__ v_b0, short* __restrict__ vbT) {
  const int bm = blockIdx.x;  // j*9+m
  const int j = bm / 9;
  const int m = bm % 9;
  const int l = (m == 0) ? 0 : ((m < 4) ? 1 : 2);
  const float* w = wT + (2 + l) * 16384;
  const int co = threadIdx.x;
  __shared__ float s[128];
  s[co] = x_emb[bm * 128 + co];
  __syncthreads();
  float acc = (m == 0) ? v_b0[co] : 0.f;
#pragma unroll 8
  for (int ci = 0; ci < 128; ++ci) acc = fmaf(s[ci], w[ci * 128 + co], acc);
  const int h = co >> 4, d = co & 15;
  vbT[(h * 144 + m * 16 + d) * 1024 + j] = f2bf(acc);
}

// ---------------------------------------------------------------------------
// K7: per head h: O[1024 x 144] = A[1024 x 1024] * V[1024 x 144]
// Fragment-direct from global: NO LDS, NO barriers. 1 wave/block, 16i x 144n
// per wave, 9 f32x4 accumulators. Grid (64 itiles, 8 heads) = 512 blocks.
// A (attn bf16 [h][i][k]) and B (vbT bf16 [h][n][k]) rows are k-contiguous:
// lane loads bf16x8 at k = q*8 — quad-neighbors cover contiguous 64 B.
// Maps (m89-verified via round 3): A[m=l15][k=q*8+r]; B[k=q*8+r][n=l15];
// D: col(n)=l15, row(i)=q*4+reg.
__global__ __launch_bounds__(64) void htr_apply_mfma(
    const short* __restrict__ attn,  // [h][i][k] bf16
    const short* __restrict__ vbT,   // [h][n][k] bf16
    float* __restrict__ obuf) {      // [i][m][c] fp32
  const int ibase = blockIdx.x * 16;
  const int h = blockIdx.y;
  const int lane = threadIdx.x;
  const int q = lane >> 4, l15 = lane & 15;
  const short* ap = attn + (h * 1024 + ibase + l15) * 1024 + q * 8;
  const short* bp = vbT + (h * 144 + l15) * 1024 + q * 8;
  f32x4 acc[9];
#pragma unroll
  for (int t = 0; t < 9; ++t) acc[t] = (f32x4){0.f, 0.f, 0.f, 0.f};
  bf16x8 a = *(const bf16x8*)ap;
  bf16x8 b[9];
#pragma unroll
  for (int t = 0; t < 9; ++t) b[t] = *(const bf16x8*)(bp + t * 16384);
  for (int ks = 1; ks < 32; ++ks) {
    const int off = ks * 32;
    bf16x8 an = *(const bf16x8*)(ap + off);
    bf16x8 bn[9];
#pragma unroll
    for (int t = 0; t < 9; ++t)
      bn[t] = *(const bf16x8*)(bp + t * 16384 + off);
#pragma unroll
    for (int t = 0; t < 9; ++t)
      acc[t] = __builtin_amdgcn_mfma_f32_16x16x32_bf16(a, b[t], acc[t], 0, 0, 0);
    a = an;
#pragma unroll
    for (int t = 0; t < 9; ++t) b[t] = bn[t];
  }
#pragma unroll
  for (int t = 0; t < 9; ++t)
    acc[t] = __builtin_amdgcn_mfma_f32_16x16x32_bf16(a, b[t], acc[t], 0, 0, 0);
#pragma unroll
  for (int t = 0; t < 9; ++t) {  // n = t*16+l15 -> m = t, d = l15
#pragma unroll
    for (int r = 0; r < 4; ++r) {
      int i = ibase + q * 4 + r;
      obuf[(i * 9 + t) * 128 + h * 16 + l15] = acc[t][r];
    }
  }
}

// ---------------------------------------------------------------------------
// K8: out[i,m,:] = LayerNorm(x_emb[i,m,:] + obuf[i,m,:] @ out_w[l]^T)
__global__ __launch_bounds__(128) void htr_outln(
    const float* __restrict__ x_emb, const float* __restrict__ obuf,
    const float* __restrict__ wT, const float* __restrict__ ln_g,
    const float* __restrict__ ln_b, float* __restrict__ out) {
  const int bm = blockIdx.x;  // i*9+m
  const int m = bm % 9;
  const int l = (m == 0) ? 0 : ((m < 4) ? 1 : 2);
  const float* w = wT + (5 + l) * 16384;
  const int co = threadIdx.x;
  __shared__ float s[128];
  __shared__ float r1[2], r2[2];
  s[co] = obuf[bm * 128 + co];
  __syncthreads();
  float acc = 0.f;
#pragma unroll 8
  for (int ci = 0; ci < 128; ++ci) acc = fmaf(s[ci], w[ci * 128 + co], acc);
  float t = x_emb[bm * 128 + co] + acc;
  const int wave = co >> 6, lane = co & 63;
  float sv = wave_sum(t);
  float sq = wave_sum(t * t);
  if (lane == 0) { r1[wave] = sv; r2[wave] = sq; }
  __syncthreads();
  const float mu = (r1[0] + r1[1]) * (1.0f / 128.0f);
  const float ms = (r2[0] + r2[1]) * (1.0f / 128.0f);
  const float var = ms - mu * mu;
  out[bm * 128 + co] =
      (t - mu) * rsqrtf(var + 1e-5f) * ln_g[l * 128 + co] + ln_b[l * 128 + co];
}

// ---------------------------------------------------------------------------
extern "C" void kernel_launch(void* const* d_in, const int* in_sizes, int n_in,
                              void* d_out, int out_size, void* d_ws, size_t ws_size,
                              hipStream_t stream) {
  (void)in_sizes; (void)n_in; (void)out_size; (void)ws_size;
  const float* x_emb = (const float*)d_in[0];
  const float* pos   = (const float*)d_in[1];
  const float* q_w   = (const float*)d_in[2];
  const float* q_b   = (const float*)d_in[3];
  const float* k_w   = (const float*)d_in[4];
  const float* k_b   = (const float*)d_in[5];
  const float* v_w   = (const float*)d_in[6];
  const float* v_b0  = (const float*)d_in[7];
  const float* out_w = (const float*)d_in[8];
  const float* ln_g  = (const float*)d_in[9];
  const float* ln_b  = (const float*)d_in[10];
  const int*   batch = (const int*)d_in[11];
  float* out = (float*)d_out;

  // workspace layout (float offsets)
  float* ws    = (float*)d_ws;
  float* S_row = ws;              //   9,216
  float* rowm  = ws + 16384;      // 131,072
  float* colm  = ws + 147456;     // 131,072
  float* qbuf  = ws + 278528;     // 131,072
  float* khbuf = ws + 409600;     // 131,072  [h][j][d]
  float* wT    = ws + 540672;     // 131,072
  short* vbT   = (short*)(ws + 671744);   // 1,179,648 bf16 [h][n][k]
  float* obuf  = ws + 1851392;    // 1,179,648
  short* attn  = (short*)(ws + 3031040);  // 8,388,608 bf16 [h][i][j]
  float* part  = ws + 3031040;    // colmean partials alias attn region
                                  // (attn written only after reduce)

  htr_transpose<<<8, 256, 0, stream>>>(q_w, k_w, v_w, out_w, wT);
  htr_row_stats<<<1024, 256, 0, stream>>>(pos, batch, S_row);
  htr_rowmean<<<1024, 128, 0, stream>>>(x_emb, S_row, rowm);
  htr_colmean<<<dim3(1024 / CM_J, CM_ISPLIT), 256, 0, stream>>>(x_emb, pos,
                                                                batch, part);
  htr_reduce<<<512, 256, 0, stream>>>(part, colm, 131072, CM_ISPLIT,
                                      1.0f / 1024.0f);
  htr_qk<<<2048, 128, 0, stream>>>(rowm, colm, wT, q_b, k_b, qbuf, khbuf);
  htr_attn<<<dim3(1024, 8), 256, 0, stream>>>(qbuf, khbuf, batch, attn);
  htr_vproj<<<9216, 128, 0, stream>>>(x_emb, wT, v_b0, vbT);
  htr_apply_mfma<<<dim3(64, 8), 64, 0, stream>>>(attn, vbT, obuf);
  htr_outln<<<9216, 128, 0, stream>>>(x_emb, obuf, wT, ln_g, ln_b, out);
}

// Round 5
// 230.206 us; speedup vs baseline: 1.5743x; 1.1905x over previous
//
#include <hip/hip_runtime.h>
#include <hip/hip_bf16.h>
#include <math.h>

#define NN 1024

typedef __attribute__((ext_vector_type(8))) short bf16x8;
typedef __attribute__((ext_vector_type(4))) float f32x4;

__device__ __forceinline__ float wave_sum(float v) {
#pragma unroll
  for (int off = 32; off > 0; off >>= 1) v += __shfl_down(v, off);
  return v;
}
__device__ __forceinline__ float wave_max(float v) {
#pragma unroll
  for (int off = 32; off > 0; off >>= 1) v = fmaxf(v, __shfl_down(v, off));
  return v;
}
__device__ __forceinline__ short f2bf(float x) {
  __hip_bfloat16 b = __float2bfloat16(x);
  return *(short*)&b;
}

#define SH_C0 0.28209479177387814f
#define SH_C1 0.4886025119029199f
#define SH_S15 1.0925484305920792f
#define SH_S5 0.6307831305050401f

// ---------------------------------------------------------------------------
// K0: transpose the 8 [128x128] weight matrices so GEMV reads are coalesced.
__global__ __launch_bounds__(256) void htr_transpose(
    const float* __restrict__ qw, const float* __restrict__ kw,
    const float* __restrict__ vw, const float* __restrict__ ow,
    float* __restrict__ wT) {
  const int b = blockIdx.x;  // 0..7
  const float* src;
  if (b == 0) src = qw;
  else if (b == 1) src = kw;
  else if (b < 5) src = vw + (b - 2) * 16384;
  else src = ow + (b - 5) * 16384;
  float* dst = wT + b * 16384;
  for (int idx = threadIdx.x; idx < 16384; idx += 256) {
    int r = idx >> 7, cc = idx & 127;
    dst[cc * 128 + r] = src[idx];
  }
}

// ---------------------------------------------------------------------------
// K1: S_row[i][m] = (1/N) sum_j valid(i,j) * sh_m(r_hat(i,j))
__global__ __launch_bounds__(256) void htr_row_stats(
    const float* __restrict__ pos, const int* __restrict__ batch,
    float* __restrict__ S_row) {
  const int i = blockIdx.x;
  const int tid = threadIdx.x;
  const float px = pos[i * 3 + 0], py = pos[i * 3 + 1], pz = pos[i * 3 + 2];
  const int bi = batch[i];
  float s[9];
#pragma unroll
  for (int m = 0; m < 9; ++m) s[m] = 0.f;
  for (int j = tid; j < NN; j += 256) {
    if (j == i) continue;
    if (batch[j] != bi) continue;
    float dx = px - pos[j * 3 + 0];
    float dy = py - pos[j * 3 + 1];
    float dz = pz - pos[j * 3 + 2];
    float d2 = dx * dx + dy * dy + dz * dz;
    float dist = fmaxf(sqrtf(d2), 1e-8f);
    float inv = 1.0f / dist;
    float x = dx * inv, y = dy * inv, z = dz * inv;
    s[0] += 1.0f;
    s[1] += x; s[2] += y; s[3] += z;
    s[4] += x * z; s[5] += x * y;
    s[6] += y * y - 0.5f * (x * x + z * z);
    s[7] += y * z;
    s[8] += z * z - x * x;
  }
  __shared__ float red[4][9];
  const int wave = tid >> 6, lane = tid & 63;
#pragma unroll
  for (int m = 0; m < 9; ++m) {
    float v = wave_sum(s[m]);
    if (lane == 0) red[wave][m] = v;
  }
  __syncthreads();
  if (tid < 9) {
    float v = red[0][tid] + red[1][tid] + red[2][tid] + red[3][tid];
    float scl = SH_S15;
    if (tid == 0) scl = SH_C0;
    else if (tid < 4) scl = SH_C1;
    else if (tid == 6) scl = SH_S5;
    else if (tid == 8) scl = 0.5f * SH_S15;
    S_row[i * 9 + tid] = v * scl * (1.0f / 1024.0f);
  }
}

// ---------------------------------------------------------------------------
// K2: rowmean[i,c] = sum_m S_row[i,m] * invdeg(m) * x_emb[i,m,c]
__global__ __launch_bounds__(128) void htr_rowmean(
    const float* __restrict__ x_emb, const float* __restrict__ S_row,
    float* __restrict__ rowm) {
  const int i = blockIdx.x;
  const int c = threadIdx.x;
  float acc = 0.f;
#pragma unroll
  for (int m = 0; m < 9; ++m) {
    float idg = (m == 0) ? 1.f : ((m < 4) ? (1.f / 3.f) : 0.2f);
    acc = fmaf(S_row[i * 9 + m] * idg, x_emb[(i * 9 + m) * 128 + c], acc);
  }
  rowm[i * 128 + c] = acc;
}

// ---------------------------------------------------------------------------
// K3a: materialize Wsh[j][k], k = m*1024 + i, bf16, with sh-scale * idg *
// validity folded in. Coalesced 2B stores (consecutive i -> consecutive addr).
__global__ __launch_bounds__(256) void htr_wsh(
    const float* __restrict__ pos, const int* __restrict__ batch,
    short* __restrict__ Wsh) {
  const int j = blockIdx.x;
  const float pjx = pos[j * 3 + 0], pjy = pos[j * 3 + 1], pjz = pos[j * 3 + 2];
  const int bj = batch[j];
  short* wrow = Wsh + j * 9216;
  for (int i = threadIdx.x; i < 1024; i += 256) {
    float dx = pos[i * 3 + 0] - pjx;
    float dy = pos[i * 3 + 1] - pjy;
    float dz = pos[i * 3 + 2] - pjz;
    bool ok = (i != j) && (batch[i] == bj);
    float okf = ok ? 1.f : 0.f;
    float d2 = dx * dx + dy * dy + dz * dz;
    float inv = okf / fmaxf(sqrtf(d2), 1e-8f);
    float x = dx * inv, y = dy * inv, z = dz * inv;
    wrow[0 * 1024 + i] = f2bf(SH_C0 * okf);
    wrow[1 * 1024 + i] = f2bf((SH_C1 * (1.f / 3.f)) * x);
    wrow[2 * 1024 + i] = f2bf((SH_C1 * (1.f / 3.f)) * y);
    wrow[3 * 1024 + i] = f2bf((SH_C1 * (1.f / 3.f)) * z);
    wrow[4 * 1024 + i] = f2bf((SH_S15 * 0.2f) * x * z);
    wrow[5 * 1024 + i] = f2bf((SH_S15 * 0.2f) * x * y);
    wrow[6 * 1024 + i] = f2bf((SH_S5 * 0.2f) * (y * y - 0.5f * (x * x + z * z)));
    wrow[7 * 1024 + i] = f2bf((SH_S15 * 0.2f) * y * z);
    wrow[8 * 1024 + i] = f2bf((0.5f * SH_S15 * 0.2f) * (z * z - x * x));
  }
}

// ---------------------------------------------------------------------------
// K3b: fT[c][k], k = m*1024 + i, bf16 = x_emb[i,m,c] (idg folded into Wsh).
// LDS tile transpose: block = (i-tile of 32) x (one m).
__global__ __launch_bounds__(256) void htr_ftrans(
    const float* __restrict__ x_emb, short* __restrict__ fT) {
  const int i0 = blockIdx.x * 32;
  const int m = blockIdx.y;
  const int tid = threadIdx.x;
  __shared__ short tile[128][34];
#pragma unroll
  for (int it = 0; it < 16; ++it) {
    int e = tid + it * 256;            // 4096 = 32 rows x 128 c
    int r = e >> 7, c = e & 127;
    tile[c][r] = f2bf(x_emb[((i0 + r) * 9 + m) * 128 + c]);
  }
  __syncthreads();
#pragma unroll
  for (int it = 0; it < 8; ++it) {
    int idx = tid + it * 256;          // 2048 short2
    int c = idx >> 4, ii2 = idx & 15;
    short2 s2 = make_short2(tile[c][ii2 * 2], tile[c][ii2 * 2 + 1]);
    *(short2*)(fT + c * 9216 + m * 1024 + i0 + ii2 * 2) = s2;
  }
}

// ---------------------------------------------------------------------------
// K3c: colmean partial GEMM: part[ks][j][c] = sum_{k in chunk} W[j][k]*fT[c][k]
// Fragment-direct MFMA (same structure as htr_apply_mfma): 1 wave/block,
// no LDS, no barriers. Grid (64 j-tiles, 16 k-splits). K chunk = 576 = 18*32.
#define CMS 16
__global__ __launch_bounds__(64) void htr_colmean_mfma(
    const short* __restrict__ Wsh,  // [j][k] bf16
    const short* __restrict__ fT,   // [c][k] bf16
    float* __restrict__ part) {     // [ks][j][c] fp32
  const int jbase = blockIdx.x * 16;
  const int ks = blockIdx.y;
  const int lane = threadIdx.x;
  const int q = lane >> 4, l15 = lane & 15;
  const short* ap = Wsh + (jbase + l15) * 9216 + ks * 576 + q * 8;
  const short* bp = fT + l15 * 9216 + ks * 576 + q * 8;
  f32x4 acc[8];
#pragma unroll
  for (int t = 0; t < 8; ++t) acc[t] = (f32x4){0.f, 0.f, 0.f, 0.f};
  bf16x8 a = *(const bf16x8*)ap;
  bf16x8 b[8];
#pragma unroll
  for (int t = 0; t < 8; ++t) b[t] = *(const bf16x8*)(bp + t * 147456);
  for (int s = 1; s < 18; ++s) {
    const int off = s * 32;
    bf16x8 an = *(const bf16x8*)(ap + off);
    bf16x8 bn[8];
#pragma unroll
    for (int t = 0; t < 8; ++t)
      bn[t] = *(const bf16x8*)(bp + t * 147456 + off);
#pragma unroll
    for (int t = 0; t < 8; ++t)
      acc[t] = __builtin_amdgcn_mfma_f32_16x16x32_bf16(a, b[t], acc[t], 0, 0, 0);
    a = an;
#pragma unroll
    for (int t = 0; t < 8; ++t) b[t] = bn[t];
  }
#pragma unroll
  for (int t = 0; t < 8; ++t)
    acc[t] = __builtin_amdgcn_mfma_f32_16x16x32_bf16(a, b[t], acc[t], 0, 0, 0);
#pragma unroll
  for (int t = 0; t < 8; ++t) {
#pragma unroll
    for (int r = 0; r < 4; ++r) {
      int j = jbase + q * 4 + r;
      part[(ks * 1024 + j) * 128 + t * 16 + l15] = acc[t][r];
    }
  }
}

// ---------------------------------------------------------------------------
// K3d: dst[t] = scale * sum_s src[s*n + t]
__global__ __launch_bounds__(256) void htr_reduce(
    const float* __restrict__ src, float* __restrict__ dst, int n, int nsl,
    float scale) {
  int t = blockIdx.x * 256 + threadIdx.x;
  if (t >= n) return;
  float a = 0.f;
  for (int s = 0; s < nsl; ++s) a += src[s * n + t];
  dst[t] = a * scale;
}

// ---------------------------------------------------------------------------
// K4: q = rowmean @ q_w^T + q_b   (layout [i][c])
//     k = colmean @ k_w^T + k_b   (layout [h][j][d])
__global__ __launch_bounds__(128) void htr_qk(
    const float* __restrict__ rowm, const float* __restrict__ colm,
    const float* __restrict__ wT, const float* __restrict__ q_b,
    const float* __restrict__ k_b, float* __restrict__ qbuf,
    float* __restrict__ khbuf) {
  const int b = blockIdx.x;
  const bool isq = b < 1024;
  const int i = isq ? b : (b - 1024);
  const float* src = isq ? (rowm + i * 128) : (colm + i * 128);
  const float* w = wT + (isq ? 0 : 16384);
  const int co = threadIdx.x;
  __shared__ float s[128];
  s[co] = src[co];
  __syncthreads();
  float acc = isq ? q_b[co] : k_b[co];
#pragma unroll 8
  for (int ci = 0; ci < 128; ++ci) acc = fmaf(s[ci], w[ci * 128 + co], acc);
  if (isq) qbuf[i * 128 + co] = acc;
  else khbuf[((co >> 4) * 1024 + i) * 16 + (co & 15)] = acc;
}

// ---------------------------------------------------------------------------
// K5: attn[h,i,:] = softmax_j (q_ih . k_jh)/4, masked to same batch. BF16 out.
__global__ __launch_bounds__(256) void htr_attn(
    const float* __restrict__ qbuf, const float* __restrict__ khbuf,
    const int* __restrict__ batch, short* __restrict__ attn) {
  const int i = blockIdx.x;
  const int h = blockIdx.y;
  const int tid = threadIdx.x;
  __shared__ float qv[16];
  __shared__ float redm[4], reds[4];
  if (tid < 16) qv[tid] = qbuf[i * 128 + h * 16 + tid] * 0.25f;
  __syncthreads();
  const int bi = batch[i];
  float l[4];
#pragma unroll
  for (int p = 0; p < 4; ++p) {
    int j = tid + (p << 8);
    float acc = -INFINITY;
    if (batch[j] == bi) {
      const float4* kp = (const float4*)(khbuf + (h * 1024 + j) * 16);
      float4 k0 = kp[0], k1 = kp[1], k2 = kp[2], k3 = kp[3];
      float d = 0.f;
      d = fmaf(qv[0], k0.x, d);  d = fmaf(qv[1], k0.y, d);
      d = fmaf(qv[2], k0.z, d);  d = fmaf(qv[3], k0.w, d);
      d = fmaf(qv[4], k1.x, d);  d = fmaf(qv[5], k1.y, d);
      d = fmaf(qv[6], k1.z, d);  d = fmaf(qv[7], k1.w, d);
      d = fmaf(qv[8], k2.x, d);  d = fmaf(qv[9], k2.y, d);
      d = fmaf(qv[10], k2.z, d); d = fmaf(qv[11], k2.w, d);
      d = fmaf(qv[12], k3.x, d); d = fmaf(qv[13], k3.y, d);
      d = fmaf(qv[14], k3.z, d); d = fmaf(qv[15], k3.w, d);
      acc = d;
    }
    l[p] = acc;
  }
  const int wave = tid >> 6, lane = tid & 63;
  float mx = fmaxf(fmaxf(l[0], l[1]), fmaxf(l[2], l[3]));
  mx = wave_max(mx);
  if (lane == 0) redm[wave] = mx;
  __syncthreads();
  const float M = fmaxf(fmaxf(redm[0], redm[1]), fmaxf(redm[2], redm[3]));
  float e[4];
  float ssum = 0.f;
#pragma unroll
  for (int p = 0; p < 4; ++p) { e[p] = expf(l[p] - M); ssum += e[p]; }
  ssum = wave_sum(ssum);
  if (lane == 0) reds[wave] = ssum;
  __syncthreads();
  const float inv = 1.0f / (reds[0] + reds[1] + reds[2] + reds[3]);
  short* dstp = attn + (h * 1024 + i) * 1024;
#pragma unroll
  for (int p = 0; p < 4; ++p) dstp[tid + (p << 8)] = f2bf(e[p] * inv);
}

// ---------------------------------------------------------------------------
// K6: v = x_emb[j,m,:] @ v_w[l(m)]^T (+ v_b0 when m==0), written DIRECTLY as
// bf16 in MFMA-B layout: vbT[h][n][k] with n = m*16+d, k = j.
__global__ __launch_bounds__(128) void htr_vproj(
    const float* __restrict__ x_emb, const float* __restrict__ wT,
    const float* __restrict__ v_b0, short* __restrict__ vbT) {
  const int bm = blockIdx.x;  // j*9+m
  const int j = bm / 9;
  const int m = bm % 9;
  const int l = (m == 0) ? 0 : ((m < 4) ? 1 : 2);
  const float* w = wT + (2 + l) * 16384;
  const int co = threadIdx.x;
  __shared__ float s[128];
  s[co] = x_emb[bm * 128 + co];
  __syncthreads();
  float acc = (m == 0) ? v_b0[co] : 0.f;
#pragma unroll 8
  for (int ci = 0; ci < 128; ++ci) acc = fmaf(s[ci], w[ci * 128 + co], acc);
  const int h = co >> 4, d = co & 15;
  vbT[(h * 144 + m * 16 + d) * 1024 + j] = f2bf(acc);
}

// ---------------------------------------------------------------------------
// K7: per head h: O[1024 x 144] = A[1024 x 1024] * V[1024 x 144]
// Fragment-direct from global: NO LDS, NO barriers. 1 wave/block.
__global__ __launch_bounds__(64) void htr_apply_mfma(
    const short* __restrict__ attn,  // [h][i][k] bf16
    const short* __restrict__ vbT,   // [h][n][k] bf16
    float* __restrict__ obuf) {      // [i][m][c] fp32
  const int ibase = blockIdx.x * 16;
  const int h = blockIdx.y;
  const int lane = threadIdx.x;
  const int q = lane >> 4, l15 = lane & 15;
  const short* ap = attn + (h * 1024 + ibase + l15) * 1024 + q * 8;
  const short* bp = vbT + (h * 144 + l15) * 1024 + q * 8;
  f32x4 acc[9];
#pragma unroll
  for (int t = 0; t < 9; ++t) acc[t] = (f32x4){0.f, 0.f, 0.f, 0.f};
  bf16x8 a = *(const bf16x8*)ap;
  bf16x8 b[9];
#pragma unroll
  for (int t = 0; t < 9; ++t) b[t] = *(const bf16x8*)(bp + t * 16384);
  for (int ks = 1; ks < 32; ++ks) {
    const int off = ks * 32;
    bf16x8 an = *(const bf16x8*)(ap + off);
    bf16x8 bn[9];
#pragma unroll
    for (int t = 0; t < 9; ++t)
      bn[t] = *(const bf16x8*)(bp + t * 16384 + off);
#pragma unroll
    for (int t = 0; t < 9; ++t)
      acc[t] = __builtin_amdgcn_mfma_f32_16x16x32_bf16(a, b[t], acc[t], 0, 0, 0);
    a = an;
#pragma unroll
    for (int t = 0; t < 9; ++t) b[t] = bn[t];
  }
#pragma unroll
  for (int t = 0; t < 9; ++t)
    acc[t] = __builtin_amdgcn_mfma_f32_16x16x32_bf16(a, b[t], acc[t], 0, 0, 0);
#pragma unroll
  for (int t = 0; t < 9; ++t) {  // n = t*16+l15 -> m = t, d = l15
#pragma unroll
    for (int r = 0; r < 4; ++r) {
      int i = ibase + q * 4 + r;
      obuf[(i * 9 + t) * 128 + h * 16 + l15] = acc[t][r];
    }
  }
}

// ---------------------------------------------------------------------------
// K8: out[i,m,:] = LayerNorm(x_emb[i,m,:] + obuf[i,m,:] @ out_w[l]^T)
__global__ __launch_bounds__(128) void htr_outln(
    const float* __restrict__ x_emb, const float* __restrict__ obuf,
    const float* __restrict__ wT, const float* __restrict__ ln_g,
    const float* __restrict__ ln_b, float* __restrict__ out) {
  const int bm = blockIdx.x;  // i*9+m
  const int m = bm % 9;
  const int l = (m == 0) ? 0 : ((m < 4) ? 1 : 2);
  const float* w = wT + (5 + l) * 16384;
  const int co = threadIdx.x;
  __shared__ float s[128];
  __shared__ float r1[2], r2[2];
  s[co] = obuf[bm * 128 + co];
  __syncthreads();
  float acc = 0.f;
#pragma unroll 8
  for (int ci = 0; ci < 128; ++ci) acc = fmaf(s[ci], w[ci * 128 + co], acc);
  float t = x_emb[bm * 128 + co] + acc;
  const int wave = co >> 6, lane = co & 63;
  float sv = wave_sum(t);
  float sq = wave_sum(t * t);
  if (lane == 0) { r1[wave] = sv; r2[wave] = sq; }
  __syncthreads();
  const float mu = (r1[0] + r1[1]) * (1.0f / 128.0f);
  const float ms = (r2[0] + r2[1]) * (1.0f / 128.0f);
  const float var = ms - mu * mu;
  out[bm * 128 + co] =
      (t - mu) * rsqrtf(var + 1e-5f) * ln_g[l * 128 + co] + ln_b[l * 128 + co];
}

// ---------------------------------------------------------------------------
extern "C" void kernel_launch(void* const* d_in, const int* in_sizes, int n_in,
                              void* d_out, int out_size, void* d_ws, size_t ws_size,
                              hipStream_t stream) {
  (void)in_sizes; (void)n_in; (void)out_size; (void)ws_size;
  const float* x_emb = (const float*)d_in[0];
  const float* pos   = (const float*)d_in[1];
  const float* q_w   = (const float*)d_in[2];
  const float* q_b   = (const float*)d_in[3];
  const float* k_w   = (const float*)d_in[4];
  const float* k_b   = (const float*)d_in[5];
  const float* v_w   = (const float*)d_in[6];
  const float* v_b0  = (const float*)d_in[7];
  const float* out_w = (const float*)d_in[8];
  const float* ln_g  = (const float*)d_in[9];
  const float* ln_b  = (const float*)d_in[10];
  const int*   batch = (const int*)d_in[11];
  float* out = (float*)d_out;

  // workspace layout (float offsets). Early colmean buffers (Wsh/fT/part)
  // alias the late-phase vbT/obuf/attn regions — lifetimes disjoint:
  // colmean path runs first, its buffers are dead before vbT/attn/obuf are
  // written. Peak usage 8,077,312 floats = 32.3 MB.
  float* ws    = (float*)d_ws;
  float* S_row = ws;                         //   9,216 (pad 16,384)
  float* rowm  = ws + 16384;                 // 131,072
  float* colm  = ws + 147456;                // 131,072
  float* qbuf  = ws + 278528;                // 131,072
  float* khbuf = ws + 409600;                // 131,072  [h][j][d]
  float* wT    = ws + 540672;                // 131,072
  short* vbT   = (short*)(ws + 671744);      // 1,179,648 bf16 -> 589,824 f
  float* obuf  = ws + 1261568;               // 1,179,648
  short* attn  = (short*)(ws + 2441216);     // 8,388,608 bf16 -> 4,194,304 f
  // early-phase (aliases vbT/obuf/attn):
  short* Wsh   = (short*)(ws + 671744);      // 9,437,184 bf16 -> 4,718,592 f
  short* fT    = (short*)(ws + 5390336);     // 1,179,648 bf16 -> 589,824 f
  float* part  = ws + 5980160;               // 2,097,152 -> ends 8,077,312

  // --- colmean path first (its scratch aliases later buffers) ---
  htr_wsh<<<1024, 256, 0, stream>>>(pos, batch, Wsh);
  htr_ftrans<<<dim3(32, 9), 256, 0, stream>>>(x_emb, fT);
  htr_colmean_mfma<<<dim3(64, CMS), 64, 0, stream>>>(Wsh, fT, part);
  htr_reduce<<<512, 256, 0, stream>>>(part, colm, 131072, CMS, 1.0f / 1024.0f);
  // --- rest of the pipeline ---
  htr_transpose<<<8, 256, 0, stream>>>(q_w, k_w, v_w, out_w, wT);
  htr_row_stats<<<1024, 256, 0, stream>>>(pos, batch, S_row);
  htr_rowmean<<<1024, 128, 0, stream>>>(x_emb, S_row, rowm);
  htr_qk<<<2048, 128, 0, stream>>>(rowm, colm, wT, q_b, k_b, qbuf, khbuf);
  htr_attn<<<dim3(1024, 8), 256, 0, stream>>>(qbuf, khbuf, batch, attn);
  htr_vproj<<<9216, 128, 0, stream>>>(x_emb, wT, v_b0, vbT);
  htr_apply_mfma<<<dim3(64, 8), 64, 0, stream>>>(attn, vbT, obuf);
  htr_outln<<<9216, 128, 0, stream>>>(x_emb, obuf, wT, ln_g, ln_b, out);
}

// Round 6
// 190.851 us; speedup vs baseline: 1.8989x; 1.2062x over previous
//
#include <hip/hip_runtime.h>
#include <hip/hip_bf16.h>
#include <math.h>

#define NN 1024

typedef __attribute__((ext_vector_type(8))) short bf16x8;
typedef __attribute__((ext_vector_type(4))) float f32x4;

__device__ __forceinline__ float wave_sum(float v) {
#pragma unroll
  for (int off = 32; off > 0; off >>= 1) v += __shfl_down(v, off);
  return v;
}
__device__ __forceinline__ float wave_max(float v) {
#pragma unroll
  for (int off = 32; off > 0; off >>= 1) v = fmaxf(v, __shfl_down(v, off));
  return v;
}
__device__ __forceinline__ short f2bf(float x) {
  __hip_bfloat16 b = __float2bfloat16(x);
  return *(short*)&b;
}

#define SH_C0 0.28209479177387814f
#define SH_C1 0.4886025119029199f
#define SH_S15 1.0925484305920792f
#define SH_S5 0.6307831305050401f

// ---------------------------------------------------------------------------
// K0: prep. blocks 0..7: convert the 8 weight mats to bf16 (original [o][i]
// layout — already k-contiguous for MFMA-B). order: q,k,v0,v1,v2,o0,o1,o2.
// blocks 8..1159: x_emb -> bf16 (same [row][c] layout; MFMA-A operand).
__global__ __launch_bounds__(256) void htr_prep(
    const float* __restrict__ qw, const float* __restrict__ kw,
    const float* __restrict__ vw, const float* __restrict__ ow,
    const float* __restrict__ x_emb, short* __restrict__ wbf,
    short* __restrict__ x_bf) {
  const int b = blockIdx.x;
  const int tid = threadIdx.x;
  if (b < 8) {
    const float* src;
    if (b == 0) src = qw;
    else if (b == 1) src = kw;
    else if (b < 5) src = vw + (b - 2) * 16384;
    else src = ow + (b - 5) * 16384;
    short* dst = wbf + b * 16384;
    for (int idx = tid; idx < 16384; idx += 256) dst[idx] = f2bf(src[idx]);
  } else {
    int base = (b - 8) * 1024 + tid * 4;
    float4 v = *(const float4*)(x_emb + base);
    short4 s4 = make_short4(f2bf(v.x), f2bf(v.y), f2bf(v.z), f2bf(v.w));
    *(short4*)(x_bf + base) = s4;
  }
}

// ---------------------------------------------------------------------------
// K1: row stats + fused rowmean. S[m] = (1/N) sum_j valid * sh_m, then
// rowm_bf[i,c] = sum_m S[m]*idg(m)*x_emb[i,m,c]  (bf16 out, MFMA-A layout).
__global__ __launch_bounds__(256) void htr_row_stats(
    const float* __restrict__ pos, const int* __restrict__ batch,
    const float* __restrict__ x_emb, short* __restrict__ rowm_bf) {
  const int i = blockIdx.x;
  const int tid = threadIdx.x;
  const float px = pos[i * 3 + 0], py = pos[i * 3 + 1], pz = pos[i * 3 + 2];
  const int bi = batch[i];
  float s[9];
#pragma unroll
  for (int m = 0; m < 9; ++m) s[m] = 0.f;
  for (int j = tid; j < NN; j += 256) {
    if (j == i) continue;
    if (batch[j] != bi) continue;
    float dx = px - pos[j * 3 + 0];
    float dy = py - pos[j * 3 + 1];
    float dz = pz - pos[j * 3 + 2];
    float d2 = dx * dx + dy * dy + dz * dz;
    float inv = 1.0f / fmaxf(sqrtf(d2), 1e-8f);
    float x = dx * inv, y = dy * inv, z = dz * inv;
    s[0] += 1.0f;
    s[1] += x; s[2] += y; s[3] += z;
    s[4] += x * z; s[5] += x * y;
    s[6] += y * y - 0.5f * (x * x + z * z);
    s[7] += y * z;
    s[8] += z * z - x * x;
  }
  __shared__ float red[4][9];
  __shared__ float sm[9];
  const int wave = tid >> 6, lane = tid & 63;
#pragma unroll
  for (int m = 0; m < 9; ++m) {
    float v = wave_sum(s[m]);
    if (lane == 0) red[wave][m] = v;
  }
  __syncthreads();
  if (tid < 9) {
    float v = red[0][tid] + red[1][tid] + red[2][tid] + red[3][tid];
    float scl = SH_S15 * 0.2f;               // m = 4,5,7
    if (tid == 0) scl = SH_C0;
    else if (tid < 4) scl = SH_C1 * (1.f / 3.f);
    else if (tid == 6) scl = SH_S5 * 0.2f;
    else if (tid == 8) scl = 0.5f * SH_S15 * 0.2f;
    sm[tid] = v * scl * (1.0f / 1024.0f);    // idg folded in
  }
  __syncthreads();
  if (tid < 128) {
    float acc = 0.f;
#pragma unroll
    for (int m = 0; m < 9; ++m)
      acc = fmaf(sm[m], x_emb[(i * 9 + m) * 128 + tid], acc);
    rowm_bf[i * 128 + tid] = f2bf(acc);
  }
}

// ---------------------------------------------------------------------------
// K2a: Wsh[j][k], k = m*1024+i, bf16, sh*idg*validity folded.
__global__ __launch_bounds__(256) void htr_wsh(
    const float* __restrict__ pos, const int* __restrict__ batch,
    short* __restrict__ Wsh) {
  const int j = blockIdx.x;
  const float pjx = pos[j * 3 + 0], pjy = pos[j * 3 + 1], pjz = pos[j * 3 + 2];
  const int bj = batch[j];
  short* wrow = Wsh + j * 9216;
  for (int i = threadIdx.x; i < 1024; i += 256) {
    float dx = pos[i * 3 + 0] - pjx;
    float dy = pos[i * 3 + 1] - pjy;
    float dz = pos[i * 3 + 2] - pjz;
    bool ok = (i != j) && (batch[i] == bj);
    float okf = ok ? 1.f : 0.f;
    float d2 = dx * dx + dy * dy + dz * dz;
    float inv = okf / fmaxf(sqrtf(d2), 1e-8f);
    float x = dx * inv, y = dy * inv, z = dz * inv;
    wrow[0 * 1024 + i] = f2bf(SH_C0 * okf);
    wrow[1 * 1024 + i] = f2bf((SH_C1 * (1.f / 3.f)) * x);
    wrow[2 * 1024 + i] = f2bf((SH_C1 * (1.f / 3.f)) * y);
    wrow[3 * 1024 + i] = f2bf((SH_C1 * (1.f / 3.f)) * z);
    wrow[4 * 1024 + i] = f2bf((SH_S15 * 0.2f) * x * z);
    wrow[5 * 1024 + i] = f2bf((SH_S15 * 0.2f) * x * y);
    wrow[6 * 1024 + i] = f2bf((SH_S5 * 0.2f) * (y * y - 0.5f * (x * x + z * z)));
    wrow[7 * 1024 + i] = f2bf((SH_S15 * 0.2f) * y * z);
    wrow[8 * 1024 + i] = f2bf((0.5f * SH_S15 * 0.2f) * (z * z - x * x));
  }
}

// ---------------------------------------------------------------------------
// K2b: fT[c][k], k = m*1024+i, bf16 (LDS tile transpose of x_emb).
__global__ __launch_bounds__(256) void htr_ftrans(
    const float* __restrict__ x_emb, short* __restrict__ fT) {
  const int i0 = blockIdx.x * 32;
  const int m = blockIdx.y;
  const int tid = threadIdx.x;
  __shared__ short tile[128][34];
#pragma unroll
  for (int it = 0; it < 16; ++it) {
    int e = tid + it * 256;
    int r = e >> 7, c = e & 127;
    tile[c][r] = f2bf(x_emb[((i0 + r) * 9 + m) * 128 + c]);
  }
  __syncthreads();
#pragma unroll
  for (int it = 0; it < 8; ++it) {
    int idx = tid + it * 256;
    int c = idx >> 4, ii2 = idx & 15;
    short2 s2 = make_short2(tile[c][ii2 * 2], tile[c][ii2 * 2 + 1]);
    *(short2*)(fT + c * 9216 + m * 1024 + i0 + ii2 * 2) = s2;
  }
}

// ---------------------------------------------------------------------------
// K2c: colmean partial GEMM (fragment-direct, 1 wave, no LDS).
#define CMS 16
__global__ __launch_bounds__(64) void htr_colmean_mfma(
    const short* __restrict__ Wsh, const short* __restrict__ fT,
    float* __restrict__ part) {
  const int jbase = blockIdx.x * 16;
  const int ks = blockIdx.y;
  const int lane = threadIdx.x;
  const int q = lane >> 4, l15 = lane & 15;
  const short* ap = Wsh + (jbase + l15) * 9216 + ks * 576 + q * 8;
  const short* bp = fT + l15 * 9216 + ks * 576 + q * 8;
  f32x4 acc[8];
#pragma unroll
  for (int t = 0; t < 8; ++t) acc[t] = (f32x4){0.f, 0.f, 0.f, 0.f};
  bf16x8 a = *(const bf16x8*)ap;
  bf16x8 b[8];
#pragma unroll
  for (int t = 0; t < 8; ++t) b[t] = *(const bf16x8*)(bp + t * 147456);
  for (int s = 1; s < 18; ++s) {
    const int off = s * 32;
    bf16x8 an = *(const bf16x8*)(ap + off);
    bf16x8 bn[8];
#pragma unroll
    for (int t = 0; t < 8; ++t) bn[t] = *(const bf16x8*)(bp + t * 147456 + off);
#pragma unroll
    for (int t = 0; t < 8; ++t)
      acc[t] = __builtin_amdgcn_mfma_f32_16x16x32_bf16(a, b[t], acc[t], 0, 0, 0);
    a = an;
#pragma unroll
    for (int t = 0; t < 8; ++t) b[t] = bn[t];
  }
#pragma unroll
  for (int t = 0; t < 8; ++t)
    acc[t] = __builtin_amdgcn_mfma_f32_16x16x32_bf16(a, b[t], acc[t], 0, 0, 0);
#pragma unroll
  for (int t = 0; t < 8; ++t)
#pragma unroll
    for (int r = 0; r < 4; ++r)
      part[(ks * 1024 + jbase + q * 4 + r) * 128 + t * 16 + l15] = acc[t][r];
}

// ---------------------------------------------------------------------------
// K2d: colm_bf[t] = bf16(scale * sum_s part[s*n + t])
__global__ __launch_bounds__(256) void htr_reduce_bf(
    const float* __restrict__ src, short* __restrict__ dst, int n, int nsl,
    float scale) {
  int t = blockIdx.x * 256 + threadIdx.x;
  if (t >= n) return;
  float a = 0.f;
  for (int s = 0; s < nsl; ++s) a += src[s * n + t];
  dst[t] = f2bf(a * scale);
}

// ---------------------------------------------------------------------------
// K3: q/k projection as MFMA. A = rowm_bf/colm_bf [i][k], B = q_w/k_w bf16
// [o][k] (original layout). q -> qbuf [i][c] fp32; k -> khbuf [h][j][d] fp32.
__global__ __launch_bounds__(64) void htr_qk_mfma(
    const short* __restrict__ rowm_bf, const short* __restrict__ colm_bf,
    const short* __restrict__ wbf, const float* __restrict__ q_b,
    const float* __restrict__ k_b, float* __restrict__ qbuf,
    float* __restrict__ khbuf) {
  const int ibase = blockIdx.x * 16;
  const bool isq = (blockIdx.y == 0);
  const short* src = isq ? rowm_bf : colm_bf;
  const short* wp = isq ? wbf : (wbf + 16384);
  const float* bias = isq ? q_b : k_b;
  const int lane = threadIdx.x;
  const int q = lane >> 4, l15 = lane & 15;
  const short* ap = src + (ibase + l15) * 128 + q * 8;
  const short* bp = wp + l15 * 128 + q * 8;
  bf16x8 a[4];
#pragma unroll
  for (int ks = 0; ks < 4; ++ks) a[ks] = *(const bf16x8*)(ap + ks * 32);
  f32x4 acc[8];
#pragma unroll
  for (int t = 0; t < 8; ++t) {
    acc[t] = (f32x4){0.f, 0.f, 0.f, 0.f};
    const short* bt = bp + t * 2048;
#pragma unroll
    for (int ks = 0; ks < 4; ++ks) {
      bf16x8 b = *(const bf16x8*)(bt + ks * 32);
      acc[t] = __builtin_amdgcn_mfma_f32_16x16x32_bf16(a[ks], b, acc[t], 0, 0, 0);
    }
  }
#pragma unroll
  for (int t = 0; t < 8; ++t) {
    float bo = bias[t * 16 + l15];
#pragma unroll
    for (int r = 0; r < 4; ++r) {
      int j = ibase + q * 4 + r;
      float val = acc[t][r] + bo;
      if (isq) qbuf[j * 128 + t * 16 + l15] = val;
      else khbuf[(t * 1024 + j) * 16 + l15] = val;
    }
  }
}

// ---------------------------------------------------------------------------
// K4: attn, 8 i-rows per block, q in VGPRs (k reused across 4 i per thread).
// grid (128, 8), 256 thr: group g = tid>>7 handles 4 i's; 128 threads span j.
__global__ __launch_bounds__(256) void htr_attn8(
    const float* __restrict__ qbuf, const float* __restrict__ khbuf,
    const int* __restrict__ batch, short* __restrict__ attn) {
  const int ibase = blockIdx.x * 8;
  const int h = blockIdx.y;
  const int tid = threadIdx.x;
  const int g = tid >> 7;
  const int lj = tid & 127;
  const int i0 = ibase + g * 4;
  float qr[4][16];
  int bi[4];
#pragma unroll
  for (int r = 0; r < 4; ++r) {
    bi[r] = batch[i0 + r];
#pragma unroll
    for (int d = 0; d < 16; ++d)
      qr[r][d] = qbuf[(i0 + r) * 128 + h * 16 + d] * 0.25f;
  }
  float s[4][8];
#pragma unroll
  for (int jt = 0; jt < 8; ++jt) {
    int j = jt * 128 + lj;
    int bj = batch[j];
    const float4* kp = (const float4*)(khbuf + (h * 1024 + j) * 16);
    float4 k0 = kp[0], k1 = kp[1], k2 = kp[2], k3 = kp[3];
#pragma unroll
    for (int r = 0; r < 4; ++r) {
      float d = 0.f;
      d = fmaf(qr[r][0], k0.x, d);  d = fmaf(qr[r][1], k0.y, d);
      d = fmaf(qr[r][2], k0.z, d);  d = fmaf(qr[r][3], k0.w, d);
      d = fmaf(qr[r][4], k1.x, d);  d = fmaf(qr[r][5], k1.y, d);
      d = fmaf(qr[r][6], k1.z, d);  d = fmaf(qr[r][7], k1.w, d);
      d = fmaf(qr[r][8], k2.x, d);  d = fmaf(qr[r][9], k2.y, d);
      d = fmaf(qr[r][10], k2.z, d); d = fmaf(qr[r][11], k2.w, d);
      d = fmaf(qr[r][12], k3.x, d); d = fmaf(qr[r][13], k3.y, d);
      d = fmaf(qr[r][14], k3.z, d); d = fmaf(qr[r][15], k3.w, d);
      s[r][jt] = (bj == bi[r]) ? d : -INFINITY;
    }
  }
  const int wig = (tid >> 6) & 1, lane = tid & 63;
  __shared__ float redm[2][4][2], reds[2][4][2];
#pragma unroll
  for (int r = 0; r < 4; ++r) {
    float mx = s[r][0];
#pragma unroll
    for (int jt = 1; jt < 8; ++jt) mx = fmaxf(mx, s[r][jt]);
    mx = wave_max(mx);
    if (lane == 0) redm[g][r][wig] = mx;
  }
  __syncthreads();
  float M[4];
#pragma unroll
  for (int r = 0; r < 4; ++r) M[r] = fmaxf(redm[g][r][0], redm[g][r][1]);
#pragma unroll
  for (int r = 0; r < 4; ++r) {
    float t = 0.f;
#pragma unroll
    for (int jt = 0; jt < 8; ++jt) {
      s[r][jt] = expf(s[r][jt] - M[r]);
      t += s[r][jt];
    }
    t = wave_sum(t);
    if (lane == 0) reds[g][r][wig] = t;
  }
  __syncthreads();
#pragma unroll
  for (int r = 0; r < 4; ++r) {
    float inv = 1.0f / (reds[g][r][0] + reds[g][r][1]);
    short* dp = attn + (h * 1024 + i0 + r) * 1024;
#pragma unroll
    for (int jt = 0; jt < 8; ++jt) dp[jt * 128 + lj] = f2bf(s[r][jt] * inv);
  }
}

// ---------------------------------------------------------------------------
// K5: v-projection as MFMA: per (16 j's, m): C[j][o] = x[j,m,:]@v_w[l]^T.
// Output bf16 vbT[h][n=m*16+d][k=j] (B operand of apply).
__global__ __launch_bounds__(64) void htr_vproj_mfma(
    const short* __restrict__ x_bf, const short* __restrict__ wbf,
    const float* __restrict__ v_b0, short* __restrict__ vbT) {
  const int jbase = blockIdx.x * 16;
  const int m = blockIdx.y;
  const int l = (m == 0) ? 0 : ((m < 4) ? 1 : 2);
  const int lane = threadIdx.x;
  const int q = lane >> 4, l15 = lane & 15;
  const short* ap = x_bf + ((jbase + l15) * 9 + m) * 128 + q * 8;
  const short* bp = wbf + (2 + l) * 16384 + l15 * 128 + q * 8;
  bf16x8 a[4];
#pragma unroll
  for (int ks = 0; ks < 4; ++ks) a[ks] = *(const bf16x8*)(ap + ks * 32);
  f32x4 acc[8];
#pragma unroll
  for (int t = 0; t < 8; ++t) {
    acc[t] = (f32x4){0.f, 0.f, 0.f, 0.f};
    const short* bt = bp + t * 2048;
#pragma unroll
    for (int ks = 0; ks < 4; ++ks) {
      bf16x8 b = *(const bf16x8*)(bt + ks * 32);
      acc[t] = __builtin_amdgcn_mfma_f32_16x16x32_bf16(a[ks], b, acc[t], 0, 0, 0);
    }
  }
#pragma unroll
  for (int t = 0; t < 8; ++t) {
    float bias = (m == 0) ? v_b0[t * 16 + l15] : 0.f;
#pragma unroll
    for (int r = 0; r < 4; ++r)
      vbT[(t * 144 + m * 16 + l15) * 1024 + jbase + q * 4 + r] =
          f2bf(acc[t][r] + bias);
  }
}

// ---------------------------------------------------------------------------
// K6: attention apply: per head O[1024x144] = A[1024x1024] @ V[1024x144].
// Fragment-direct, 1 wave, no LDS. Output bf16 (A operand of outln).
__global__ __launch_bounds__(64) void htr_apply_mfma(
    const short* __restrict__ attn, const short* __restrict__ vbT,
    short* __restrict__ obuf_bf) {
  const int ibase = blockIdx.x * 16;
  const int h = blockIdx.y;
  const int lane = threadIdx.x;
  const int q = lane >> 4, l15 = lane & 15;
  const short* ap = attn + (h * 1024 + ibase + l15) * 1024 + q * 8;
  const short* bp = vbT + (h * 144 + l15) * 1024 + q * 8;
  f32x4 acc[9];
#pragma unroll
  for (int t = 0; t < 9; ++t) acc[t] = (f32x4){0.f, 0.f, 0.f, 0.f};
  bf16x8 a = *(const bf16x8*)ap;
  bf16x8 b[9];
#pragma unroll
  for (int t = 0; t < 9; ++t) b[t] = *(const bf16x8*)(bp + t * 16384);
  for (int ks = 1; ks < 32; ++ks) {
    const int off = ks * 32;
    bf16x8 an = *(const bf16x8*)(ap + off);
    bf16x8 bn[9];
#pragma unroll
    for (int t = 0; t < 9; ++t) bn[t] = *(const bf16x8*)(bp + t * 16384 + off);
#pragma unroll
    for (int t = 0; t < 9; ++t)
      acc[t] = __builtin_amdgcn_mfma_f32_16x16x32_bf16(a, b[t], acc[t], 0, 0, 0);
    a = an;
#pragma unroll
    for (int t = 0; t < 9; ++t) b[t] = bn[t];
  }
#pragma unroll
  for (int t = 0; t < 9; ++t)
    acc[t] = __builtin_amdgcn_mfma_f32_16x16x32_bf16(a, b[t], acc[t], 0, 0, 0);
#pragma unroll
  for (int t = 0; t < 9; ++t)
#pragma unroll
    for (int r = 0; r < 4; ++r)
      obuf_bf[((ibase + q * 4 + r) * 9 + t) * 128 + h * 16 + l15] =
          f2bf(acc[t][r]);
}

// ---------------------------------------------------------------------------
// K7: out-projection + residual + LayerNorm, fused MFMA. Per (16 i's, m):
// C = obuf[i,m,:]@out_w[l]^T; t = x_emb + C; LN across 128 via shfl_xor
// within the 16-lane n-groups (lanes sharing q hold all 128 o's of a row).
__global__ __launch_bounds__(64) void htr_outln_mfma(
    const short* __restrict__ obuf_bf, const float* __restrict__ x_emb,
    const short* __restrict__ wbf, const float* __restrict__ ln_g,
    const float* __restrict__ ln_b, float* __restrict__ out) {
  const int ibase = blockIdx.x * 16;
  const int m = blockIdx.y;
  const int l = (m == 0) ? 0 : ((m < 4) ? 1 : 2);
  const int lane = threadIdx.x;
  const int q = lane >> 4, l15 = lane & 15;
  const short* ap = obuf_bf + ((ibase + l15) * 9 + m) * 128 + q * 8;
  const short* bp = wbf + (5 + l) * 16384 + l15 * 128 + q * 8;
  bf16x8 a[4];
#pragma unroll
  for (int ks = 0; ks < 4; ++ks) a[ks] = *(const bf16x8*)(ap + ks * 32);
  f32x4 acc[8];
#pragma unroll
  for (int t = 0; t < 8; ++t) {
    acc[t] = (f32x4){0.f, 0.f, 0.f, 0.f};
    const short* bt = bp + t * 2048;
#pragma unroll
    for (int ks = 0; ks < 4; ++ks) {
      bf16x8 b = *(const bf16x8*)(bt + ks * 32);
      acc[t] = __builtin_amdgcn_mfma_f32_16x16x32_bf16(a[ks], b, acc[t], 0, 0, 0);
    }
  }
  float g[8], bb[8];
#pragma unroll
  for (int t = 0; t < 8; ++t) {
    g[t] = ln_g[l * 128 + t * 16 + l15];
    bb[t] = ln_b[l * 128 + t * 16 + l15];
  }
#pragma unroll
  for (int r = 0; r < 4; ++r) {
    const int i = ibase + q * 4 + r;
    const float* xr = x_emb + (i * 9 + m) * 128;
    float v[8];
    float sv = 0.f, sq = 0.f;
#pragma unroll
    for (int t = 0; t < 8; ++t) {
      v[t] = acc[t][r] + xr[t * 16 + l15];
      sv += v[t];
      sq += v[t] * v[t];
    }
#pragma unroll
    for (int off = 1; off < 16; off <<= 1) {
      sv += __shfl_xor(sv, off);
      sq += __shfl_xor(sq, off);
    }
    float mu = sv * (1.f / 128.f);
    float var = sq * (1.f / 128.f) - mu * mu;
    float rs = rsqrtf(var + 1e-5f);
    float* orow = out + (i * 9 + m) * 128;
#pragma unroll
    for (int t = 0; t < 8; ++t)
      orow[t * 16 + l15] = (v[t] - mu) * rs * g[t] + bb[t];
  }
}

// ---------------------------------------------------------------------------
extern "C" void kernel_launch(void* const* d_in, const int* in_sizes, int n_in,
                              void* d_out, int out_size, void* d_ws, size_t ws_size,
                              hipStream_t stream) {
  (void)in_sizes; (void)n_in; (void)out_size; (void)ws_size;
  const float* x_emb = (const float*)d_in[0];
  const float* pos   = (const float*)d_in[1];
  const float* q_w   = (const float*)d_in[2];
  const float* q_b   = (const float*)d_in[3];
  const float* k_w   = (const float*)d_in[4];
  const float* k_b   = (const float*)d_in[5];
  const float* v_w   = (const float*)d_in[6];
  const float* v_b0  = (const float*)d_in[7];
  const float* out_w = (const float*)d_in[8];
  const float* ln_g  = (const float*)d_in[9];
  const float* ln_b  = (const float*)d_in[10];
  const int*   batch = (const int*)d_in[11];
  float* out = (float*)d_out;

  // workspace layout (float-slot offsets; total 11,730,944 f = 46.9 MB).
  // part aliases the attn region (dead before attn is written).
  float* ws = (float*)d_ws;
  short* rowm_bf = (short*)(ws + 0);         //  131,072 bf16 (65,536 f)
  short* colm_bf = (short*)(ws + 65536);     //  131,072 bf16
  float* qbuf    = ws + 131072;              //  131,072 f
  float* khbuf   = ws + 262144;              //  131,072 f  [h][j][d]
  short* wbf     = (short*)(ws + 393216);    //  131,072 bf16 (8 mats)
  short* x_bf    = (short*)(ws + 458752);    //  1,179,648 bf16
  short* vbT     = (short*)(ws + 1048576);   //  1,179,648 bf16 [h][n][k]
  short* obuf_bf = (short*)(ws + 1638400);   //  1,179,648 bf16
  short* attn    = (short*)(ws + 2228224);   //  8,388,608 bf16 [h][i][j]
  float* part    = ws + 2228224;             //  2,097,152 f (aliases attn)
  short* Wsh     = (short*)(ws + 6422528);   //  9,437,184 bf16
  short* fT      = (short*)(ws + 11141120);  //  1,179,648 bf16

  htr_prep<<<1160, 256, 0, stream>>>(q_w, k_w, v_w, out_w, x_emb, wbf, x_bf);
  htr_wsh<<<1024, 256, 0, stream>>>(pos, batch, Wsh);
  htr_ftrans<<<dim3(32, 9), 256, 0, stream>>>(x_emb, fT);
  htr_colmean_mfma<<<dim3(64, CMS), 64, 0, stream>>>(Wsh, fT, part);
  htr_reduce_bf<<<512, 256, 0, stream>>>(part, colm_bf, 131072, CMS,
                                         1.0f / 1024.0f);
  htr_row_stats<<<1024, 256, 0, stream>>>(pos, batch, x_emb, rowm_bf);
  htr_qk_mfma<<<dim3(64, 2), 64, 0, stream>>>(rowm_bf, colm_bf, wbf, q_b, k_b,
                                              qbuf, khbuf);
  htr_attn8<<<dim3(128, 8), 256, 0, stream>>>(qbuf, khbuf, batch, attn);
  htr_vproj_mfma<<<dim3(64, 9), 64, 0, stream>>>(x_bf, wbf, v_b0, vbT);
  htr_apply_mfma<<<dim3(64, 8), 64, 0, stream>>>(attn, vbT, obuf_bf);
  htr_outln_mfma<<<dim3(64, 9), 64, 0, stream>>>(obuf_bf, x_emb, wbf, ln_g,
                                                 ln_b, out);
}

// Round 7
// 172.874 us; speedup vs baseline: 2.0964x; 1.1040x over previous
//
#include <hip/hip_runtime.h>
#include <hip/hip_bf16.h>
#include <math.h>

#define NN 1024

typedef __attribute__((ext_vector_type(8))) short bf16x8;
typedef __attribute__((ext_vector_type(4))) float f32x4;

__device__ __forceinline__ float wave_sum(float v) {
#pragma unroll
  for (int off = 32; off > 0; off >>= 1) v += __shfl_down(v, off);
  return v;
}
__device__ __forceinline__ float wave_max(float v) {
#pragma unroll
  for (int off = 32; off > 0; off >>= 1) v = fmaxf(v, __shfl_down(v, off));
  return v;
}
__device__ __forceinline__ short f2bf(float x) {
  __hip_bfloat16 b = __float2bfloat16(x);
  return *(short*)&b;
}

#define SH_C0 0.28209479177387814f
#define SH_C1 0.4886025119029199f
#define SH_S15 1.0925484305920792f
#define SH_S5 0.6307831305050401f

// ---------------------------------------------------------------------------
// K1: fused independent staging. Block ranges:
//   [0,8)        : 8 weight mats fp32 -> bf16 (order q,k,v0,v1,v2,o0,o1,o2)
//   [8,1160)     : x_emb -> bf16 (x_bf, MFMA-A layout = original layout)
//   [1160,1448)  : fT[c][k=m*1024+i] bf16 (LDS tile transpose)
//   [1448,2472)  : Wsh[j][k=m*1024+i] bf16 (sh*idg*valid folded)
//   [2472,3496)  : row stats + fused rowmean -> rowm_bf (bf16)
__global__ __launch_bounds__(256) void htr_geom(
    const float* __restrict__ qw, const float* __restrict__ kw,
    const float* __restrict__ vw, const float* __restrict__ ow,
    const float* __restrict__ x_emb, const float* __restrict__ pos,
    const int* __restrict__ batch, short* __restrict__ wbf,
    short* __restrict__ x_bf, short* __restrict__ fT,
    short* __restrict__ Wsh, short* __restrict__ rowm_bf) {
  const int b = blockIdx.x;
  const int tid = threadIdx.x;
  __shared__ short tile[128][34];
  __shared__ float red[4][9];
  __shared__ float sm[9];

  if (b < 8) {
    const float* src;
    if (b == 0) src = qw;
    else if (b == 1) src = kw;
    else if (b < 5) src = vw + (b - 2) * 16384;
    else src = ow + (b - 5) * 16384;
    short* dst = wbf + b * 16384;
    for (int idx = tid; idx < 16384; idx += 256) dst[idx] = f2bf(src[idx]);
  } else if (b < 1160) {
    int base = (b - 8) * 1024 + tid * 4;
    float4 v = *(const float4*)(x_emb + base);
    *(short4*)(x_bf + base) = make_short4(f2bf(v.x), f2bf(v.y), f2bf(v.z), f2bf(v.w));
  } else if (b < 1448) {
    const int sub = b - 1160;
    const int i0 = (sub & 31) * 32;
    const int m = sub >> 5;
#pragma unroll
    for (int it = 0; it < 16; ++it) {
      int e = tid + it * 256;
      int r = e >> 7, c = e & 127;
      tile[c][r] = f2bf(x_emb[((i0 + r) * 9 + m) * 128 + c]);
    }
    __syncthreads();
#pragma unroll
    for (int it = 0; it < 8; ++it) {
      int idx = tid + it * 256;
      int c = idx >> 4, ii2 = idx & 15;
      *(short2*)(fT + c * 9216 + m * 1024 + i0 + ii2 * 2) =
          make_short2(tile[c][ii2 * 2], tile[c][ii2 * 2 + 1]);
    }
  } else if (b < 2472) {
    const int j = b - 1448;
    const float pjx = pos[j * 3 + 0], pjy = pos[j * 3 + 1], pjz = pos[j * 3 + 2];
    const int bj = batch[j];
    short* wrow = Wsh + j * 9216;
    for (int i = tid; i < 1024; i += 256) {
      float dx = pos[i * 3 + 0] - pjx;
      float dy = pos[i * 3 + 1] - pjy;
      float dz = pos[i * 3 + 2] - pjz;
      bool ok = (i != j) && (batch[i] == bj);
      float okf = ok ? 1.f : 0.f;
      float d2 = dx * dx + dy * dy + dz * dz;
      float inv = okf / fmaxf(sqrtf(d2), 1e-8f);
      float x = dx * inv, y = dy * inv, z = dz * inv;
      wrow[0 * 1024 + i] = f2bf(SH_C0 * okf);
      wrow[1 * 1024 + i] = f2bf((SH_C1 * (1.f / 3.f)) * x);
      wrow[2 * 1024 + i] = f2bf((SH_C1 * (1.f / 3.f)) * y);
      wrow[3 * 1024 + i] = f2bf((SH_C1 * (1.f / 3.f)) * z);
      wrow[4 * 1024 + i] = f2bf((SH_S15 * 0.2f) * x * z);
      wrow[5 * 1024 + i] = f2bf((SH_S15 * 0.2f) * x * y);
      wrow[6 * 1024 + i] = f2bf((SH_S5 * 0.2f) * (y * y - 0.5f * (x * x + z * z)));
      wrow[7 * 1024 + i] = f2bf((SH_S15 * 0.2f) * y * z);
      wrow[8 * 1024 + i] = f2bf((0.5f * SH_S15 * 0.2f) * (z * z - x * x));
    }
  } else {
    const int i = b - 2472;
    const float px = pos[i * 3 + 0], py = pos[i * 3 + 1], pz = pos[i * 3 + 2];
    const int bi = batch[i];
    float s[9];
#pragma unroll
    for (int m = 0; m < 9; ++m) s[m] = 0.f;
    for (int j = tid; j < NN; j += 256) {
      if (j == i) continue;
      if (batch[j] != bi) continue;
      float dx = px - pos[j * 3 + 0];
      float dy = py - pos[j * 3 + 1];
      float dz = pz - pos[j * 3 + 2];
      float d2 = dx * dx + dy * dy + dz * dz;
      float inv = 1.0f / fmaxf(sqrtf(d2), 1e-8f);
      float x = dx * inv, y = dy * inv, z = dz * inv;
      s[0] += 1.0f;
      s[1] += x; s[2] += y; s[3] += z;
      s[4] += x * z; s[5] += x * y;
      s[6] += y * y - 0.5f * (x * x + z * z);
      s[7] += y * z;
      s[8] += z * z - x * x;
    }
    const int wave = tid >> 6, lane = tid & 63;
#pragma unroll
    for (int m = 0; m < 9; ++m) {
      float v = wave_sum(s[m]);
      if (lane == 0) red[wave][m] = v;
    }
    __syncthreads();
    if (tid < 9) {
      float v = red[0][tid] + red[1][tid] + red[2][tid] + red[3][tid];
      float scl = SH_S15 * 0.2f;
      if (tid == 0) scl = SH_C0;
      else if (tid < 4) scl = SH_C1 * (1.f / 3.f);
      else if (tid == 6) scl = SH_S5 * 0.2f;
      else if (tid == 8) scl = 0.5f * SH_S15 * 0.2f;
      sm[tid] = v * scl * (1.0f / 1024.0f);
    }
    __syncthreads();
    if (tid < 128) {
      float acc = 0.f;
#pragma unroll
      for (int m = 0; m < 9; ++m)
        acc = fmaf(sm[m], x_emb[(i * 9 + m) * 128 + tid], acc);
      rowm_bf[i * 128 + tid] = f2bf(acc);
    }
  }
}

// ---------------------------------------------------------------------------
// K2: colmean partial GEMM (fragment-direct, 1 wave, no LDS).
// part[ks][j][c] = sum over k-chunk of Wsh[j][k]*fT[c][k].
#define CMS 16
__global__ __launch_bounds__(64) void htr_colmean_mfma(
    const short* __restrict__ Wsh, const short* __restrict__ fT,
    float* __restrict__ part) {
  const int jbase = blockIdx.x * 16;
  const int ks = blockIdx.y;
  const int lane = threadIdx.x;
  const int q = lane >> 4, l15 = lane & 15;
  const short* ap = Wsh + (jbase + l15) * 9216 + ks * 576 + q * 8;
  const short* bp = fT + l15 * 9216 + ks * 576 + q * 8;
  f32x4 acc[8];
#pragma unroll
  for (int t = 0; t < 8; ++t) acc[t] = (f32x4){0.f, 0.f, 0.f, 0.f};
  bf16x8 a = *(const bf16x8*)ap;
  bf16x8 b[8];
#pragma unroll
  for (int t = 0; t < 8; ++t) b[t] = *(const bf16x8*)(bp + t * 147456);
  for (int s = 1; s < 18; ++s) {
    const int off = s * 32;
    bf16x8 an = *(const bf16x8*)(ap + off);
    bf16x8 bn[8];
#pragma unroll
    for (int t = 0; t < 8; ++t) bn[t] = *(const bf16x8*)(bp + t * 147456 + off);
#pragma unroll
    for (int t = 0; t < 8; ++t)
      acc[t] = __builtin_amdgcn_mfma_f32_16x16x32_bf16(a, b[t], acc[t], 0, 0, 0);
    a = an;
#pragma unroll
    for (int t = 0; t < 8; ++t) b[t] = bn[t];
  }
#pragma unroll
  for (int t = 0; t < 8; ++t)
    acc[t] = __builtin_amdgcn_mfma_f32_16x16x32_bf16(a, b[t], acc[t], 0, 0, 0);
#pragma unroll
  for (int t = 0; t < 8; ++t)
#pragma unroll
    for (int r = 0; r < 4; ++r)
      part[(ks * 1024 + jbase + q * 4 + r) * 128 + t * 16 + l15] = acc[t][r];
}

// ---------------------------------------------------------------------------
// K3: fused projections, 1-wave MFMA blocks, grid (64, 11):
//   y==0: q = rowm @ q_w^T + q_b          -> qbuf  [i][c] fp32
//   y==1: k = colm @ k_w^T + k_b          -> khbuf [h][j][d] fp32
//         (colm built inline: fp32 sum of the 16 part slices, then bf16)
//   y>=2: v[m=y-2] = x @ v_w[l]^T (+b0)   -> vbT   [h][n][k=j] bf16
__global__ __launch_bounds__(64) void htr_proj(
    const short* __restrict__ rowm_bf, const float* __restrict__ part,
    const short* __restrict__ x_bf, const short* __restrict__ wbf,
    const float* __restrict__ q_b, const float* __restrict__ k_b,
    const float* __restrict__ v_b0, float* __restrict__ qbuf,
    float* __restrict__ khbuf, short* __restrict__ vbT) {
  const int ibase = blockIdx.x * 16;
  const int y = blockIdx.y;
  const int lane = threadIdx.x;
  const int q = lane >> 4, l15 = lane & 15;

  bf16x8 a[4];
  const short* bp;
  if (y == 0) {
    const short* ap = rowm_bf + (ibase + l15) * 128 + q * 8;
#pragma unroll
    for (int ks = 0; ks < 4; ++ks) a[ks] = *(const bf16x8*)(ap + ks * 32);
    bp = wbf + l15 * 128 + q * 8;
  } else if (y == 1) {
    const float* pp = part + (size_t)(ibase + l15) * 128;
#pragma unroll
    for (int ks = 0; ks < 4; ++ks) {
      float s0 = 0.f, s1 = 0.f, s2 = 0.f, s3 = 0.f;
      float s4 = 0.f, s5 = 0.f, s6 = 0.f, s7 = 0.f;
#pragma unroll
      for (int s = 0; s < CMS; ++s) {
        const float* ps = pp + s * 131072 + ks * 32 + q * 8;
        float4 u0 = *(const float4*)(ps);
        float4 u1 = *(const float4*)(ps + 4);
        s0 += u0.x; s1 += u0.y; s2 += u0.z; s3 += u0.w;
        s4 += u1.x; s5 += u1.y; s6 += u1.z; s7 += u1.w;
      }
      const float sc = 1.0f / 1024.0f;
      bf16x8 av;
      av[0] = f2bf(s0 * sc); av[1] = f2bf(s1 * sc);
      av[2] = f2bf(s2 * sc); av[3] = f2bf(s3 * sc);
      av[4] = f2bf(s4 * sc); av[5] = f2bf(s5 * sc);
      av[6] = f2bf(s6 * sc); av[7] = f2bf(s7 * sc);
      a[ks] = av;
    }
    bp = wbf + 16384 + l15 * 128 + q * 8;
  } else {
    const int m = y - 2;
    const int l = (m == 0) ? 0 : ((m < 4) ? 1 : 2);
    const short* ap = x_bf + ((ibase + l15) * 9 + m) * 128 + q * 8;
#pragma unroll
    for (int ks = 0; ks < 4; ++ks) a[ks] = *(const bf16x8*)(ap + ks * 32);
    bp = wbf + (2 + l) * 16384 + l15 * 128 + q * 8;
  }

  f32x4 acc[8];
#pragma unroll
  for (int t = 0; t < 8; ++t) {
    acc[t] = (f32x4){0.f, 0.f, 0.f, 0.f};
    const short* bt = bp + t * 2048;
#pragma unroll
    for (int ks = 0; ks < 4; ++ks) {
      bf16x8 b = *(const bf16x8*)(bt + ks * 32);
      acc[t] = __builtin_amdgcn_mfma_f32_16x16x32_bf16(a[ks], b, acc[t], 0, 0, 0);
    }
  }

  if (y == 0) {
#pragma unroll
    for (int t = 0; t < 8; ++t) {
      float bo = q_b[t * 16 + l15];
#pragma unroll
      for (int r = 0; r < 4; ++r)
        qbuf[(ibase + q * 4 + r) * 128 + t * 16 + l15] = acc[t][r] + bo;
    }
  } else if (y == 1) {
#pragma unroll
    for (int t = 0; t < 8; ++t) {
      float bo = k_b[t * 16 + l15];
#pragma unroll
      for (int r = 0; r < 4; ++r)
        khbuf[(t * 1024 + ibase + q * 4 + r) * 16 + l15] = acc[t][r] + bo;
    }
  } else {
    const int m = y - 2;
#pragma unroll
    for (int t = 0; t < 8; ++t) {
      float bias = (m == 0) ? v_b0[t * 16 + l15] : 0.f;
#pragma unroll
      for (int r = 0; r < 4; ++r)
        vbT[(t * 144 + m * 16 + l15) * 1024 + ibase + q * 4 + r] =
            f2bf(acc[t][r] + bias);
    }
  }
}

// ---------------------------------------------------------------------------
// K4: attn, 8 i-rows per block, q in VGPRs. grid (128, 8), 256 thr.
__global__ __launch_bounds__(256) void htr_attn8(
    const float* __restrict__ qbuf, const float* __restrict__ khbuf,
    const int* __restrict__ batch, short* __restrict__ attn) {
  const int ibase = blockIdx.x * 8;
  const int h = blockIdx.y;
  const int tid = threadIdx.x;
  const int g = tid >> 7;
  const int lj = tid & 127;
  const int i0 = ibase + g * 4;
  float qr[4][16];
  int bi[4];
#pragma unroll
  for (int r = 0; r < 4; ++r) {
    bi[r] = batch[i0 + r];
#pragma unroll
    for (int d = 0; d < 16; ++d)
      qr[r][d] = qbuf[(i0 + r) * 128 + h * 16 + d] * 0.25f;
  }
  float s[4][8];
#pragma unroll
  for (int jt = 0; jt < 8; ++jt) {
    int j = jt * 128 + lj;
    int bj = batch[j];
    const float4* kp = (const float4*)(khbuf + (h * 1024 + j) * 16);
    float4 k0 = kp[0], k1 = kp[1], k2 = kp[2], k3 = kp[3];
#pragma unroll
    for (int r = 0; r < 4; ++r) {
      float d = 0.f;
      d = fmaf(qr[r][0], k0.x, d);  d = fmaf(qr[r][1], k0.y, d);
      d = fmaf(qr[r][2], k0.z, d);  d = fmaf(qr[r][3], k0.w, d);
      d = fmaf(qr[r][4], k1.x, d);  d = fmaf(qr[r][5], k1.y, d);
      d = fmaf(qr[r][6], k1.z, d);  d = fmaf(qr[r][7], k1.w, d);
      d = fmaf(qr[r][8], k2.x, d);  d = fmaf(qr[r][9], k2.y, d);
      d = fmaf(qr[r][10], k2.z, d); d = fmaf(qr[r][11], k2.w, d);
      d = fmaf(qr[r][12], k3.x, d); d = fmaf(qr[r][13], k3.y, d);
      d = fmaf(qr[r][14], k3.z, d); d = fmaf(qr[r][15], k3.w, d);
      s[r][jt] = (bj == bi[r]) ? d : -INFINITY;
    }
  }
  const int wig = (tid >> 6) & 1, lane = tid & 63;
  __shared__ float redm[2][4][2], reds[2][4][2];
#pragma unroll
  for (int r = 0; r < 4; ++r) {
    float mx = s[r][0];
#pragma unroll
    for (int jt = 1; jt < 8; ++jt) mx = fmaxf(mx, s[r][jt]);
    mx = wave_max(mx);
    if (lane == 0) redm[g][r][wig] = mx;
  }
  __syncthreads();
  float M[4];
#pragma unroll
  for (int r = 0; r < 4; ++r) M[r] = fmaxf(redm[g][r][0], redm[g][r][1]);
#pragma unroll
  for (int r = 0; r < 4; ++r) {
    float t = 0.f;
#pragma unroll
    for (int jt = 0; jt < 8; ++jt) {
      s[r][jt] = expf(s[r][jt] - M[r]);
      t += s[r][jt];
    }
    t = wave_sum(t);
    if (lane == 0) reds[g][r][wig] = t;
  }
  __syncthreads();
#pragma unroll
  for (int r = 0; r < 4; ++r) {
    float inv = 1.0f / (reds[g][r][0] + reds[g][r][1]);
    short* dp = attn + (h * 1024 + i0 + r) * 1024;
#pragma unroll
    for (int jt = 0; jt < 8; ++jt) dp[jt * 128 + lj] = f2bf(s[r][jt] * inv);
  }
}

// ---------------------------------------------------------------------------
// K5: attention apply, n-split for occupancy: grid (64, 8, 2).
template <int NT0, int NT>
__device__ __forceinline__ void apply_body(
    const short* __restrict__ attn, const short* __restrict__ vbT,
    short* __restrict__ obuf_bf, int ibase, int h, int lane) {
  const int q = lane >> 4, l15 = lane & 15;
  const short* ap = attn + (h * 1024 + ibase + l15) * 1024 + q * 8;
  const short* bp = vbT + (h * 144 + l15) * 1024 + q * 8;
  f32x4 acc[NT];
#pragma unroll
  for (int t = 0; t < NT; ++t) acc[t] = (f32x4){0.f, 0.f, 0.f, 0.f};
  bf16x8 a = *(const bf16x8*)ap;
  bf16x8 b[NT];
#pragma unroll
  for (int t = 0; t < NT; ++t) b[t] = *(const bf16x8*)(bp + (NT0 + t) * 16384);
  for (int ks = 1; ks < 32; ++ks) {
    const int off = ks * 32;
    bf16x8 an = *(const bf16x8*)(ap + off);
    bf16x8 bn[NT];
#pragma unroll
    for (int t = 0; t < NT; ++t)
      bn[t] = *(const bf16x8*)(bp + (NT0 + t) * 16384 + off);
#pragma unroll
    for (int t = 0; t < NT; ++t)
      acc[t] = __builtin_amdgcn_mfma_f32_16x16x32_bf16(a, b[t], acc[t], 0, 0, 0);
    a = an;
#pragma unroll
    for (int t = 0; t < NT; ++t) b[t] = bn[t];
  }
#pragma unroll
  for (int t = 0; t < NT; ++t)
    acc[t] = __builtin_amdgcn_mfma_f32_16x16x32_bf16(a, b[t], acc[t], 0, 0, 0);
#pragma unroll
  for (int t = 0; t < NT; ++t)
#pragma unroll
    for (int r = 0; r < 4; ++r)
      obuf_bf[((ibase + q * 4 + r) * 9 + NT0 + t) * 128 + h * 16 + l15] =
          f2bf(acc[t][r]);
}

__global__ __launch_bounds__(64) void htr_apply_mfma(
    const short* __restrict__ attn, const short* __restrict__ vbT,
    short* __restrict__ obuf_bf) {
  const int ibase = blockIdx.x * 16;
  const int h = blockIdx.y;
  if (blockIdx.z == 0)
    apply_body<0, 5>(attn, vbT, obuf_bf, ibase, h, threadIdx.x);
  else
    apply_body<5, 4>(attn, vbT, obuf_bf, ibase, h, threadIdx.x);
}

// ---------------------------------------------------------------------------
// K6: out-projection + residual + LayerNorm (fused MFMA epilogue).
__global__ __launch_bounds__(64) void htr_outln_mfma(
    const short* __restrict__ obuf_bf, const float* __restrict__ x_emb,
    const short* __restrict__ wbf, const float* __restrict__ ln_g,
    const float* __restrict__ ln_b, float* __restrict__ out) {
  const int ibase = blockIdx.x * 16;
  const int m = blockIdx.y;
  const int l = (m == 0) ? 0 : ((m < 4) ? 1 : 2);
  const int lane = threadIdx.x;
  const int q = lane >> 4, l15 = lane & 15;
  const short* ap = obuf_bf + ((ibase + l15) * 9 + m) * 128 + q * 8;
  const short* bp = wbf + (5 + l) * 16384 + l15 * 128 + q * 8;
  bf16x8 a[4];
#pragma unroll
  for (int ks = 0; ks < 4; ++ks) a[ks] = *(const bf16x8*)(ap + ks * 32);
  f32x4 acc[8];
#pragma unroll
  for (int t = 0; t < 8; ++t) {
    acc[t] = (f32x4){0.f, 0.f, 0.f, 0.f};
    const short* bt = bp + t * 2048;
#pragma unroll
    for (int ks = 0; ks < 4; ++ks) {
      bf16x8 b = *(const bf16x8*)(bt + ks * 32);
      acc[t] = __builtin_amdgcn_mfma_f32_16x16x32_bf16(a[ks], b, acc[t], 0, 0, 0);
    }
  }
  float g[8], bb[8];
#pragma unroll
  for (int t = 0; t < 8; ++t) {
    g[t] = ln_g[l * 128 + t * 16 + l15];
    bb[t] = ln_b[l * 128 + t * 16 + l15];
  }
#pragma unroll
  for (int r = 0; r < 4; ++r) {
    const int i = ibase + q * 4 + r;
    const float* xr = x_emb + (i * 9 + m) * 128;
    float v[8];
    float sv = 0.f, sq = 0.f;
#pragma unroll
    for (int t = 0; t < 8; ++t) {
      v[t] = acc[t][r] + xr[t * 16 + l15];
      sv += v[t];
      sq += v[t] * v[t];
    }
#pragma unroll
    for (int off = 1; off < 16; off <<= 1) {
      sv += __shfl_xor(sv, off);
      sq += __shfl_xor(sq, off);
    }
    float mu = sv * (1.f / 128.f);
    float var = sq * (1.f / 128.f) - mu * mu;
    float rs = rsqrtf(var + 1e-5f);
    float* orow = out + (i * 9 + m) * 128;
#pragma unroll
    for (int t = 0; t < 8; ++t)
      orow[t * 16 + l15] = (v[t] - mu) * rs * g[t] + bb[t];
  }
}

// ---------------------------------------------------------------------------
extern "C" void kernel_launch(void* const* d_in, const int* in_sizes, int n_in,
                              void* d_out, int out_size, void* d_ws, size_t ws_size,
                              hipStream_t stream) {
  (void)in_sizes; (void)n_in; (void)out_size; (void)ws_size;
  const float* x_emb = (const float*)d_in[0];
  const float* pos   = (const float*)d_in[1];
  const float* q_w   = (const float*)d_in[2];
  const float* q_b   = (const float*)d_in[3];
  const float* k_w   = (const float*)d_in[4];
  const float* k_b   = (const float*)d_in[5];
  const float* v_w   = (const float*)d_in[6];
  const float* v_b0  = (const float*)d_in[7];
  const float* out_w = (const float*)d_in[8];
  const float* ln_g  = (const float*)d_in[9];
  const float* ln_b  = (const float*)d_in[10];
  const int*   batch = (const int*)d_in[11];
  float* out = (float*)d_out;

  // workspace (float-slot offsets; total 11,665,408 f = 46.7 MB).
  // part aliases attn: part is produced by colmean, consumed by proj (y==1),
  // and dead before attn8 writes attn.
  float* ws = (float*)d_ws;
  short* rowm_bf = (short*)(ws + 0);         //   131,072 bf16
  float* qbuf    = ws + 65536;               //   131,072 f
  float* khbuf   = ws + 196608;              //   131,072 f  [h][j][d]
  short* wbf     = (short*)(ws + 327680);    //   131,072 bf16 (8 mats)
  short* x_bf    = (short*)(ws + 393216);    // 1,179,648 bf16
  short* vbT     = (short*)(ws + 983040);    // 1,179,648 bf16 [h][n][k]
  short* obuf_bf = (short*)(ws + 1572864);   // 1,179,648 bf16
  short* attn    = (short*)(ws + 2162688);   // 8,388,608 bf16 [h][i][j]
  float* part    = ws + 2162688;             // 2,097,152 f (aliases attn)
  short* Wsh     = (short*)(ws + 6356992);   // 9,437,184 bf16
  short* fT      = (short*)(ws + 11075584);  // 1,179,648 bf16

  htr_geom<<<3496, 256, 0, stream>>>(q_w, k_w, v_w, out_w, x_emb, pos, batch,
                                     wbf, x_bf, fT, Wsh, rowm_bf);
  htr_colmean_mfma<<<dim3(64, CMS), 64, 0, stream>>>(Wsh, fT, part);
  htr_proj<<<dim3(64, 11), 64, 0, stream>>>(rowm_bf, part, x_bf, wbf, q_b, k_b,
                                            v_b0, qbuf, khbuf, vbT);
  htr_attn8<<<dim3(128, 8), 256, 0, stream>>>(qbuf, khbuf, batch, attn);
  htr_apply_mfma<<<dim3(64, 8, 2), 64, 0, stream>>>(attn, vbT, obuf_bf);
  htr_outln_mfma<<<dim3(64, 9), 64, 0, stream>>>(obuf_bf, x_emb, wbf, ln_g,
                                                 ln_b, out);
}